// Round 1
// baseline (1529.221 us; speedup 1.0000x reference)
//
#include <hip/hip_runtime.h>
#include <hip/hip_bf16.h>

// GCNConv: out = scatter_add_row( norm[e] * (x@W)[col[e]] ) + bias
//   deg = bincount(row); norm[e] = deg[row]^-.5 * deg[col]^-.5
// N=100000 nodes, E=1.7M edges, C=128 channels, fp32 throughout.

// ---------------- deg count ----------------
__global__ void deg_kernel(const int* __restrict__ row, float* __restrict__ deg, int E) {
    int g = blockIdx.x * blockDim.x + threadIdx.x;
    if (g < E) atomicAdd(&deg[row[g]], 1.0f);
}

// ---------------- deg^-0.5 in place ----------------
__global__ void rsqrt_kernel(float* __restrict__ deg, int N) {
    int g = blockIdx.x * blockDim.x + threadIdx.x;
    if (g < N) deg[g] = rsqrtf(deg[g]);
}

// ---------------- GEMM: S[N,128] = X[N,128] @ W[128,128] ----------------
// Block: 256 threads (16x16), tile 64 rows x 128 cols, K-chunks of 32.
#define GB_M 64
#define GB_KC 32
__global__ __launch_bounds__(256) void gemm_kernel(const float* __restrict__ X,
                                                   const float* __restrict__ W,
                                                   float* __restrict__ S, int N) {
    __shared__ float sXT[GB_KC][72];   // [k][n], row = 288B (16B aligned), padded
    __shared__ float sW[GB_KC][128];   // [k][o]
    const int t  = threadIdx.x;
    const int tx = t & 15;   // col group
    const int ty = t >> 4;   // row group
    const int bm = blockIdx.x * GB_M;

    float acc[4][8];
#pragma unroll
    for (int i = 0; i < 4; ++i)
#pragma unroll
        for (int j = 0; j < 8; ++j) acc[i][j] = 0.f;

    const int sr = t >> 2;          // 0..63  (x row within tile)
    const int sc = (t & 3) << 2;    // 0,4,8,12

    for (int k0 = 0; k0 < 128; k0 += GB_KC) {
        // stage X tile transposed: sXT[k][n]
#pragma unroll
        for (int h = 0; h < 2; ++h) {
            int kk = sc + h * 16;
            int gr = bm + sr;
            float4 v = make_float4(0.f, 0.f, 0.f, 0.f);
            if (gr < N) v = *(const float4*)(X + (size_t)gr * 128 + k0 + kk);
            sXT[kk + 0][sr] = v.x;
            sXT[kk + 1][sr] = v.y;
            sXT[kk + 2][sr] = v.z;
            sXT[kk + 3][sr] = v.w;
        }
        // stage W tile: 32x128 floats = 1024 float4, 4 per thread
#pragma unroll
        for (int h = 0; h < 4; ++h) {
            int idx = t + h * 256;
            int wk  = idx >> 5;
            int wo  = (idx & 31) << 2;
            *(float4*)&sW[wk][wo] = *(const float4*)(W + (size_t)(k0 + wk) * 128 + wo);
        }
        __syncthreads();
#pragma unroll
        for (int k = 0; k < GB_KC; ++k) {
            float4 a  = *(const float4*)&sXT[k][ty * 4];
            float4 b0 = *(const float4*)&sW[k][tx * 4];
            float4 b1 = *(const float4*)&sW[k][64 + tx * 4];
            float av[4] = {a.x, a.y, a.z, a.w};
            float bv[8] = {b0.x, b0.y, b0.z, b0.w, b1.x, b1.y, b1.z, b1.w};
#pragma unroll
            for (int i = 0; i < 4; ++i)
#pragma unroll
                for (int j = 0; j < 8; ++j) acc[i][j] += av[i] * bv[j];
        }
        __syncthreads();
    }
#pragma unroll
    for (int i = 0; i < 4; ++i) {
        int gr = bm + ty * 4 + i;
        if (gr < N) {
            *(float4*)(S + (size_t)gr * 128 + tx * 4) =
                make_float4(acc[i][0], acc[i][1], acc[i][2], acc[i][3]);
            *(float4*)(S + (size_t)gr * 128 + 64 + tx * 4) =
                make_float4(acc[i][4], acc[i][5], acc[i][6], acc[i][7]);
        }
    }
}

// ---------------- out init: out[n][c] = bias[c] ----------------
__global__ void init_out_kernel(float* __restrict__ out, const float* __restrict__ bias,
                                int total4) {
    int g = blockIdx.x * blockDim.x + threadIdx.x;
    if (g < total4) {
        int c4 = (g & 31) << 2;   // 32 float4 per 128-ch row
        *(float4*)(out + (size_t)g * 4) = *(const float4*)(bias + c4);
    }
}

// ---------------- scatter: one wave per edge, 2 ch per lane ----------------
__global__ __launch_bounds__(256) void scatter_kernel(const int* __restrict__ row,
                                                      const int* __restrict__ col,
                                                      const float* __restrict__ dis,
                                                      const float* __restrict__ sup,
                                                      float* __restrict__ out, int E) {
    int g    = blockIdx.x * blockDim.x + threadIdx.x;
    int e    = g >> 6;
    int lane = g & 63;
    if (e >= E) return;
    int r = row[e];
    int c = col[e];
    float nrm = dis[r] * dis[c];
    float2 v = *(const float2*)(sup + (size_t)c * 128 + lane * 2);
    float* dst = out + (size_t)r * 128 + lane * 2;
    atomicAdd(dst,     nrm * v.x);
    atomicAdd(dst + 1, nrm * v.y);
}

extern "C" void kernel_launch(void* const* d_in, const int* in_sizes, int n_in,
                              void* d_out, int out_size, void* d_ws, size_t ws_size,
                              hipStream_t stream) {
    const float* x    = (const float*)d_in[0];
    const int*   ei   = (const int*)d_in[1];
    const float* W    = (const float*)d_in[2];
    const float* bias = (const float*)d_in[3];
    float*       out  = (float*)d_out;

    const int N = in_sizes[0] / 128;
    const int E = in_sizes[1] / 2;
    const int* row = ei;
    const int* col = ei + E;

    // workspace layout: deg/dis [N floats], support [N*128 floats]
    float* deg = (float*)d_ws;
    size_t sup_off = ((size_t)N * sizeof(float) + 511) & ~(size_t)511;
    float* sup = (float*)((char*)d_ws + sup_off);

    hipMemsetAsync(deg, 0, (size_t)N * sizeof(float), stream);

    deg_kernel<<<(E + 255) / 256, 256, 0, stream>>>(row, deg, E);
    rsqrt_kernel<<<(N + 255) / 256, 256, 0, stream>>>(deg, N);

    gemm_kernel<<<(N + GB_M - 1) / GB_M, 256, 0, stream>>>(x, W, sup, N);

    int total4 = N * 32;  // N*128/4
    init_out_kernel<<<(total4 + 255) / 256, 256, 0, stream>>>(out, bias, total4);

    long long sthreads = (long long)E * 64;
    int sblocks = (int)((sthreads + 255) / 256);
    scatter_kernel<<<sblocks, 256, 0, stream>>>(row, col, deg, sup, out, E);
}

// Round 2
// 385.679 us; speedup vs baseline: 3.9650x; 3.9650x over previous
//
#include <hip/hip_runtime.h>
#include <hip/hip_bf16.h>

// GCNConv: out = scatter_add_row( norm[e] * (x@W)[col[e]] ) + bias
// Round 2: replace 217.6M-atomic scatter with CSR-by-destination + gather.

// ---------------- deg histogram (int) ----------------
__global__ void deg_i_kernel(const int* __restrict__ row, int* __restrict__ degi, int E) {
    int g = blockIdx.x * blockDim.x + threadIdx.x;
    if (g < E) atomicAdd(&degi[row[g]], 1);
}

// ---------------- dis = rsqrt(deg) ----------------
__global__ void rsqrt_i_kernel(const int* __restrict__ degi, float* __restrict__ dis, int N) {
    int g = blockIdx.x * blockDim.x + threadIdx.x;
    if (g < N) dis[g] = rsqrtf((float)degi[g]);
}

// ---------------- prefix scan (3-step) ----------------
#define SCAN_B 256
__global__ void scan_block_kernel(const int* __restrict__ degi, int* __restrict__ start,
                                  int* __restrict__ bsum, int N) {
    __shared__ int s[SCAN_B];
    int t = threadIdx.x;
    int g = blockIdx.x * SCAN_B + t;
    int v = (g < N) ? degi[g] : 0;
    s[t] = v;
    __syncthreads();
#pragma unroll
    for (int off = 1; off < SCAN_B; off <<= 1) {
        int u = (t >= off) ? s[t - off] : 0;
        __syncthreads();
        s[t] += u;
        __syncthreads();
    }
    if (g < N) start[g] = s[t] - v;               // exclusive
    if (t == SCAN_B - 1) bsum[blockIdx.x] = s[t]; // block total
}

__global__ void scan_bsum_kernel(int* __restrict__ bsum, int NB) {
    __shared__ int s[1024];
    int t = threadIdx.x;
    int v = (t < NB) ? bsum[t] : 0;
    s[t] = v;
    __syncthreads();
#pragma unroll
    for (int off = 1; off < 1024; off <<= 1) {
        int u = (t >= off) ? s[t - off] : 0;
        __syncthreads();
        s[t] += u;
        __syncthreads();
    }
    if (t < NB) bsum[t] = s[t] - v;               // exclusive block offsets
}

__global__ void scan_add_kernel(int* __restrict__ start, const int* __restrict__ bsum, int N) {
    int g = blockIdx.x * blockDim.x + threadIdx.x;
    if (g < N) start[g] += bsum[g >> 8];
}

// ---------------- CSR fill: start[] bumps to inclusive ----------------
__global__ void fill_kernel(const int* __restrict__ row, const int* __restrict__ col,
                            int* __restrict__ start, int* __restrict__ csr, int E) {
    int e = blockIdx.x * blockDim.x + threadIdx.x;
    if (e < E) {
        int pos = atomicAdd(&start[row[e]], 1);
        csr[pos] = col[e];
    }
}

// ---------------- GEMM: S[N,128] = X[N,128] @ W[128,128] ----------------
#define GB_M 64
#define GB_KC 32
__global__ __launch_bounds__(256) void gemm_kernel(const float* __restrict__ X,
                                                   const float* __restrict__ W,
                                                   float* __restrict__ S, int N) {
    __shared__ float sXT[GB_KC][72];
    __shared__ float sW[GB_KC][128];
    const int t  = threadIdx.x;
    const int tx = t & 15;
    const int ty = t >> 4;
    const int bm = blockIdx.x * GB_M;

    float acc[4][8];
#pragma unroll
    for (int i = 0; i < 4; ++i)
#pragma unroll
        for (int j = 0; j < 8; ++j) acc[i][j] = 0.f;

    const int sr = t >> 2;
    const int sc = (t & 3) << 2;

    for (int k0 = 0; k0 < 128; k0 += GB_KC) {
#pragma unroll
        for (int h = 0; h < 2; ++h) {
            int kk = sc + h * 16;
            int gr = bm + sr;
            float4 v = make_float4(0.f, 0.f, 0.f, 0.f);
            if (gr < N) v = *(const float4*)(X + (size_t)gr * 128 + k0 + kk);
            sXT[kk + 0][sr] = v.x;
            sXT[kk + 1][sr] = v.y;
            sXT[kk + 2][sr] = v.z;
            sXT[kk + 3][sr] = v.w;
        }
#pragma unroll
        for (int h = 0; h < 4; ++h) {
            int idx = t + h * 256;
            int wk  = idx >> 5;
            int wo  = (idx & 31) << 2;
            *(float4*)&sW[wk][wo] = *(const float4*)(W + (size_t)(k0 + wk) * 128 + wo);
        }
        __syncthreads();
#pragma unroll
        for (int k = 0; k < GB_KC; ++k) {
            float4 a  = *(const float4*)&sXT[k][ty * 4];
            float4 b0 = *(const float4*)&sW[k][tx * 4];
            float4 b1 = *(const float4*)&sW[k][64 + tx * 4];
            float av[4] = {a.x, a.y, a.z, a.w};
            float bv[8] = {b0.x, b0.y, b0.z, b0.w, b1.x, b1.y, b1.z, b1.w};
#pragma unroll
            for (int i = 0; i < 4; ++i)
#pragma unroll
                for (int j = 0; j < 8; ++j) acc[i][j] += av[i] * bv[j];
        }
        __syncthreads();
    }
#pragma unroll
    for (int i = 0; i < 4; ++i) {
        int gr = bm + ty * 4 + i;
        if (gr < N) {
            *(float4*)(S + (size_t)gr * 128 + tx * 4) =
                make_float4(acc[i][0], acc[i][1], acc[i][2], acc[i][3]);
            *(float4*)(S + (size_t)gr * 128 + 64 + tx * 4) =
                make_float4(acc[i][4], acc[i][5], acc[i][6], acc[i][7]);
        }
    }
}

// ---------------- gather: one wave per node, float2 per lane ----------------
__global__ __launch_bounds__(256) void gather_kernel(const int* __restrict__ csr,
                                                     const int* __restrict__ start,
                                                     const float* __restrict__ dis,
                                                     const float* __restrict__ sup,
                                                     const float* __restrict__ bias,
                                                     float* __restrict__ out, int N) {
    int wid  = (blockIdx.x * blockDim.x + threadIdx.x) >> 6;  // node
    int lane = threadIdx.x & 63;
    if (wid >= N) return;
    int begin = (wid == 0) ? 0 : start[wid - 1];  // start[] is inclusive post-fill
    int end   = start[wid];
    float dr  = dis[wid];
    int c2 = lane * 2;
    float2 acc = *(const float2*)(bias + c2);

    int j = begin;
    for (; j + 3 < end; j += 4) {
        int c0 = csr[j], c1 = csr[j + 1], c2i = csr[j + 2], c3 = csr[j + 3];
        float n0 = dr * dis[c0], n1 = dr * dis[c1], n2 = dr * dis[c2i], n3 = dr * dis[c3];
        float2 v0 = *(const float2*)(sup + (size_t)c0  * 128 + c2);
        float2 v1 = *(const float2*)(sup + (size_t)c1  * 128 + c2);
        float2 v2 = *(const float2*)(sup + (size_t)c2i * 128 + c2);
        float2 v3 = *(const float2*)(sup + (size_t)c3  * 128 + c2);
        acc.x += n0 * v0.x + n1 * v1.x + n2 * v2.x + n3 * v3.x;
        acc.y += n0 * v0.y + n1 * v1.y + n2 * v2.y + n3 * v3.y;
    }
    for (; j < end; ++j) {
        int c = csr[j];
        float nrm = dr * dis[c];
        float2 v = *(const float2*)(sup + (size_t)c * 128 + c2);
        acc.x += nrm * v.x;
        acc.y += nrm * v.y;
    }
    *(float2*)(out + (size_t)wid * 128 + c2) = acc;
}

// ---------------- fallback (old atomic path) ----------------
__global__ void deg_f_kernel(const int* __restrict__ row, float* __restrict__ deg, int E) {
    int g = blockIdx.x * blockDim.x + threadIdx.x;
    if (g < E) atomicAdd(&deg[row[g]], 1.0f);
}
__global__ void rsqrt_f_kernel(float* __restrict__ deg, int N) {
    int g = blockIdx.x * blockDim.x + threadIdx.x;
    if (g < N) deg[g] = rsqrtf(deg[g]);
}
__global__ void init_out_kernel(float* __restrict__ out, const float* __restrict__ bias,
                                int total4) {
    int g = blockIdx.x * blockDim.x + threadIdx.x;
    if (g < total4) {
        int c4 = (g & 31) << 2;
        *(float4*)(out + (size_t)g * 4) = *(const float4*)(bias + c4);
    }
}
__global__ __launch_bounds__(256) void scatter_kernel(const int* __restrict__ row,
                                                      const int* __restrict__ col,
                                                      const float* __restrict__ dis,
                                                      const float* __restrict__ sup,
                                                      float* __restrict__ out, int E) {
    int g    = blockIdx.x * blockDim.x + threadIdx.x;
    int e    = g >> 6;
    int lane = g & 63;
    if (e >= E) return;
    int r = row[e];
    int c = col[e];
    float nrm = dis[r] * dis[c];
    float2 v = *(const float2*)(sup + (size_t)c * 128 + lane * 2);
    float* dst = out + (size_t)r * 128 + lane * 2;
    atomicAdd(dst,     nrm * v.x);
    atomicAdd(dst + 1, nrm * v.y);
}

extern "C" void kernel_launch(void* const* d_in, const int* in_sizes, int n_in,
                              void* d_out, int out_size, void* d_ws, size_t ws_size,
                              hipStream_t stream) {
    const float* x    = (const float*)d_in[0];
    const int*   ei   = (const int*)d_in[1];
    const float* W    = (const float*)d_in[2];
    const float* bias = (const float*)d_in[3];
    float*       out  = (float*)d_out;

    const int N = in_sizes[0] / 128;
    const int E = in_sizes[1] / 2;
    const int* row = ei;
    const int* col = ei + E;

    auto al = [](size_t v) { return (v + 511) & ~(size_t)511; };
    size_t o_degi  = 0;
    size_t o_dis   = al(o_degi + (size_t)N * 4);
    size_t o_start = al(o_dis + (size_t)N * 4);
    size_t o_bsum  = al(o_start + (size_t)N * 4);
    size_t o_csr   = al(o_bsum + 4096 * 4);
    size_t o_sup   = al(o_csr + (size_t)E * 4);
    size_t need    = o_sup + (size_t)N * 512;

    char* ws = (char*)d_ws;
    const int NB = (N + SCAN_B - 1) / SCAN_B;

    if (ws_size >= need && NB <= 1024) {
        int*   degi  = (int*)(ws + o_degi);
        float* dis   = (float*)(ws + o_dis);
        int*   start = (int*)(ws + o_start);
        int*   bsum  = (int*)(ws + o_bsum);
        int*   csr   = (int*)(ws + o_csr);
        float* sup   = (float*)(ws + o_sup);

        hipMemsetAsync(degi, 0, (size_t)N * 4, stream);
        gemm_kernel<<<(N + GB_M - 1) / GB_M, 256, 0, stream>>>(x, W, sup, N);
        deg_i_kernel<<<(E + 255) / 256, 256, 0, stream>>>(row, degi, E);
        scan_block_kernel<<<NB, SCAN_B, 0, stream>>>(degi, start, bsum, N);
        scan_bsum_kernel<<<1, 1024, 0, stream>>>(bsum, NB);
        scan_add_kernel<<<NB, SCAN_B, 0, stream>>>(start, bsum, N);
        rsqrt_i_kernel<<<NB, SCAN_B, 0, stream>>>(degi, dis, N);
        fill_kernel<<<(E + 255) / 256, 256, 0, stream>>>(row, col, start, csr, E);
        long long gthreads = (long long)N * 64;
        gather_kernel<<<(int)((gthreads + 255) / 256), 256, 0, stream>>>(
            csr, start, dis, sup, bias, out, N);
    } else {
        // fallback: atomic scatter (round-1 path)
        float* deg = (float*)ws;
        size_t sup_off = al((size_t)N * 4);
        float* sup = (float*)(ws + sup_off);
        hipMemsetAsync(deg, 0, (size_t)N * 4, stream);
        deg_f_kernel<<<(E + 255) / 256, 256, 0, stream>>>(row, deg, E);
        rsqrt_f_kernel<<<(N + 255) / 256, 256, 0, stream>>>(deg, N);
        gemm_kernel<<<(N + GB_M - 1) / GB_M, 256, 0, stream>>>(x, W, sup, N);
        int total4 = N * 32;
        init_out_kernel<<<(total4 + 255) / 256, 256, 0, stream>>>(out, bias, total4);
        long long sthreads = (long long)E * 64;
        scatter_kernel<<<(int)((sthreads + 255) / 256), 256, 0, stream>>>(
            row, col, deg, sup, out, E);
    }
}

// Round 3
// 224.742 us; speedup vs baseline: 6.8043x; 1.7161x over previous
//
#include <hip/hip_runtime.h>
#include <hip/hip_bf16.h>

// GCNConv: out = scatter_add_row( norm[e] * (x@W)[col[e]] ) + bias
// Round 3: counting-sort CSR build (bucketed, LDS-atomic) to kill the
// 108MB write-amplification of the global-atomic fill.

#define SCAN_B 256
#define NBLK_P 256      // partition blocks
#define BSHIFT 9        // 512 nodes per bucket
#define NPB    512      // nodes per bucket

// ---------------- P1: per-block bucket histogram ----------------
__global__ __launch_bounds__(256) void p1_count(const int* __restrict__ row,
                                                int* __restrict__ cnt,
                                                int E, int chunk, int nbuck) {
    __shared__ int h[256];
    const int blk = blockIdx.x, t = threadIdx.x;
    for (int i = t; i < nbuck; i += 256) h[i] = 0;
    __syncthreads();
    int lo = blk * chunk, hi = min(E, lo + chunk);
    for (int e = lo + t; e < hi; e += 256) atomicAdd(&h[row[e] >> BSHIFT], 1);
    __syncthreads();
    for (int b = t; b < nbuck; b += 256) cnt[b * NBLK_P + blk] = h[b];
}

// ---------------- scan (3-step, exclusive) ----------------
__global__ void scan_block_kernel(const int* __restrict__ in, int* __restrict__ outp,
                                  int* __restrict__ bsum, int M) {
    __shared__ int s[SCAN_B];
    int t = threadIdx.x;
    int g = blockIdx.x * SCAN_B + t;
    int v = (g < M) ? in[g] : 0;
    s[t] = v;
    __syncthreads();
#pragma unroll
    for (int off = 1; off < SCAN_B; off <<= 1) {
        int u = (t >= off) ? s[t - off] : 0;
        __syncthreads();
        s[t] += u;
        __syncthreads();
    }
    if (g < M) outp[g] = s[t] - v;
    if (t == SCAN_B - 1) bsum[blockIdx.x] = s[t];
}

__global__ void scan_bsum_kernel(int* __restrict__ bsum, int NB) {
    __shared__ int s[1024];
    int t = threadIdx.x;
    int v = (t < NB) ? bsum[t] : 0;
    s[t] = v;
    __syncthreads();
#pragma unroll
    for (int off = 1; off < 1024; off <<= 1) {
        int u = (t >= off) ? s[t - off] : 0;
        __syncthreads();
        s[t] += u;
        __syncthreads();
    }
    if (t < NB) bsum[t] = s[t] - v;
}

__global__ void scan_add_kernel(int* __restrict__ outp, const int* __restrict__ bsum, int M) {
    int g = blockIdx.x * blockDim.x + threadIdx.x;
    if (g < M) outp[g] += bsum[g >> 8];
}

// ---------------- P2: partition edges into bucket-ordered pairs ----------------
__global__ __launch_bounds__(256) void p2_scatter(const int* __restrict__ row,
                                                  const int* __restrict__ col,
                                                  const int* __restrict__ off,
                                                  int2* __restrict__ part,
                                                  int E, int chunk, int nbuck) {
    __shared__ int cur[256];
    const int blk = blockIdx.x, t = threadIdx.x;
    for (int b = t; b < nbuck; b += 256) cur[b] = off[b * NBLK_P + blk];
    __syncthreads();
    int lo = blk * chunk, hi = min(E, lo + chunk);
    for (int e = lo + t; e < hi; e += 256) {
        int r = row[e], c = col[e];
        int pos = atomicAdd(&cur[r >> BSHIFT], 1);
        part[pos] = make_int2(r, c);
    }
}

// ---------------- P3: per-bucket CSR build (one block per bucket) ----------------
__global__ __launch_bounds__(256) void p3_build(const int2* __restrict__ part,
                                                const int* __restrict__ off,
                                                int* __restrict__ rowptr,
                                                float* __restrict__ dis,
                                                int* __restrict__ csr,
                                                int N, int E, int nbuck) {
    __shared__ int hist[NPB];
    __shared__ int lstart[NPB];
    __shared__ int s[256];
    const int b = blockIdx.x, t = threadIdx.x;
    const int base_node = b << BSHIFT;
    const int csr_base  = off[b * NBLK_P];
    const int end_b     = (b == nbuck - 1) ? E : off[(b + 1) * NBLK_P];

    for (int i = t; i < NPB; i += 256) hist[i] = 0;
    __syncthreads();
    for (int e = csr_base + t; e < end_b; e += 256)
        atomicAdd(&hist[part[e].x - base_node], 1);
    __syncthreads();

    // exclusive scan of hist[0..511] with 256 threads
    int a0 = hist[2 * t], a1 = hist[2 * t + 1];
    s[t] = a0 + a1;
    __syncthreads();
    int v = s[t];
#pragma unroll
    for (int o = 1; o < 256; o <<= 1) {
        int u = (t >= o) ? s[t - o] : 0;
        __syncthreads();
        s[t] += u;
        __syncthreads();
    }
    int ex = s[t] - v;
    lstart[2 * t]     = ex;
    lstart[2 * t + 1] = ex + a0;
    __syncthreads();

    // rowptr + dis (coalesced)
    for (int i = t; i < NPB; i += 256) {
        int node = base_node + i;
        if (node < N) {
            rowptr[node] = csr_base + lstart[i];
            dis[node]    = rsqrtf((float)hist[i]);
        }
    }
    __syncthreads();
    // reuse hist as running cursor
    for (int i = t; i < NPB; i += 256) hist[i] = lstart[i];
    __syncthreads();
    for (int e = csr_base + t; e < end_b; e += 256) {
        int2 p = part[e];
        int pos = csr_base + atomicAdd(&hist[p.x - base_node], 1);
        csr[pos] = p.y;
    }
    if (b == 0 && t == 0) rowptr[N] = E;
}

// ---------------- GEMM: S[N,128] = X[N,128] @ W[128,128] ----------------
#define GB_M 64
#define GB_KC 32
__global__ __launch_bounds__(256) void gemm_kernel(const float* __restrict__ X,
                                                   const float* __restrict__ W,
                                                   float* __restrict__ S, int N) {
    __shared__ float sXT[GB_KC][72];
    __shared__ float sW[GB_KC][128];
    const int t  = threadIdx.x;
    const int tx = t & 15;
    const int ty = t >> 4;
    const int bm = blockIdx.x * GB_M;

    float acc[4][8];
#pragma unroll
    for (int i = 0; i < 4; ++i)
#pragma unroll
        for (int j = 0; j < 8; ++j) acc[i][j] = 0.f;

    const int sr = t >> 2;
    const int sc = (t & 3) << 2;

    for (int k0 = 0; k0 < 128; k0 += GB_KC) {
#pragma unroll
        for (int h = 0; h < 2; ++h) {
            int kk = sc + h * 16;
            int gr = bm + sr;
            float4 v = make_float4(0.f, 0.f, 0.f, 0.f);
            if (gr < N) v = *(const float4*)(X + (size_t)gr * 128 + k0 + kk);
            sXT[kk + 0][sr] = v.x;
            sXT[kk + 1][sr] = v.y;
            sXT[kk + 2][sr] = v.z;
            sXT[kk + 3][sr] = v.w;
        }
#pragma unroll
        for (int h = 0; h < 4; ++h) {
            int idx = t + h * 256;
            int wk  = idx >> 5;
            int wo  = (idx & 31) << 2;
            *(float4*)&sW[wk][wo] = *(const float4*)(W + (size_t)(k0 + wk) * 128 + wo);
        }
        __syncthreads();
#pragma unroll
        for (int k = 0; k < GB_KC; ++k) {
            float4 a  = *(const float4*)&sXT[k][ty * 4];
            float4 b0 = *(const float4*)&sW[k][tx * 4];
            float4 b1 = *(const float4*)&sW[k][64 + tx * 4];
            float av[4] = {a.x, a.y, a.z, a.w};
            float bv[8] = {b0.x, b0.y, b0.z, b0.w, b1.x, b1.y, b1.z, b1.w};
#pragma unroll
            for (int i = 0; i < 4; ++i)
#pragma unroll
                for (int j = 0; j < 8; ++j) acc[i][j] += av[i] * bv[j];
        }
        __syncthreads();
    }
#pragma unroll
    for (int i = 0; i < 4; ++i) {
        int gr = bm + ty * 4 + i;
        if (gr < N) {
            *(float4*)(S + (size_t)gr * 128 + tx * 4) =
                make_float4(acc[i][0], acc[i][1], acc[i][2], acc[i][3]);
            *(float4*)(S + (size_t)gr * 128 + 64 + tx * 4) =
                make_float4(acc[i][4], acc[i][5], acc[i][6], acc[i][7]);
        }
    }
}

// ---------------- gather: one wave per node, float2 per lane ----------------
__global__ __launch_bounds__(256) void gather_kernel(const int* __restrict__ csr,
                                                     const int* __restrict__ rowptr,
                                                     const float* __restrict__ dis,
                                                     const float* __restrict__ sup,
                                                     const float* __restrict__ bias,
                                                     float* __restrict__ out, int N) {
    int wid  = (blockIdx.x * blockDim.x + threadIdx.x) >> 6;
    int lane = threadIdx.x & 63;
    if (wid >= N) return;
    int begin = rowptr[wid];
    int end   = rowptr[wid + 1];
    float dr  = dis[wid];
    int ch = lane * 2;
    float2 acc = *(const float2*)(bias + ch);

    int j = begin;
    for (; j + 3 < end; j += 4) {
        int c0 = csr[j], c1 = csr[j + 1], c2i = csr[j + 2], c3 = csr[j + 3];
        float n0 = dr * dis[c0], n1 = dr * dis[c1], n2 = dr * dis[c2i], n3 = dr * dis[c3];
        float2 v0 = *(const float2*)(sup + (size_t)c0  * 128 + ch);
        float2 v1 = *(const float2*)(sup + (size_t)c1  * 128 + ch);
        float2 v2 = *(const float2*)(sup + (size_t)c2i * 128 + ch);
        float2 v3 = *(const float2*)(sup + (size_t)c3  * 128 + ch);
        acc.x += n0 * v0.x + n1 * v1.x + n2 * v2.x + n3 * v3.x;
        acc.y += n0 * v0.y + n1 * v1.y + n2 * v2.y + n3 * v3.y;
    }
    for (; j < end; ++j) {
        int c = csr[j];
        float nrm = dr * dis[c];
        float2 v = *(const float2*)(sup + (size_t)c * 128 + ch);
        acc.x += nrm * v.x;
        acc.y += nrm * v.y;
    }
    *(float2*)(out + (size_t)wid * 128 + ch) = acc;
}

// ---------------- round-2 fallback kernels ----------------
__global__ void deg_i_kernel(const int* __restrict__ row, int* __restrict__ degi, int E) {
    int g = blockIdx.x * blockDim.x + threadIdx.x;
    if (g < E) atomicAdd(&degi[row[g]], 1);
}
__global__ void rsqrt_i_kernel(const int* __restrict__ degi, float* __restrict__ dis, int N) {
    int g = blockIdx.x * blockDim.x + threadIdx.x;
    if (g < N) dis[g] = rsqrtf((float)degi[g]);
}
__global__ void fill_kernel(const int* __restrict__ row, const int* __restrict__ col,
                            int* __restrict__ start, int* __restrict__ csr, int E) {
    int e = blockIdx.x * blockDim.x + threadIdx.x;
    if (e < E) {
        int pos = atomicAdd(&start[row[e]], 1);
        csr[pos] = col[e];
    }
}
__global__ void rowptr_from_start_kernel(const int* __restrict__ degi,
                                         const int* __restrict__ startv,
                                         int* __restrict__ rowptr, int N, int E) {
    int g = blockIdx.x * blockDim.x + threadIdx.x;
    if (g < N) rowptr[g] = startv[g];
    if (g == 0) rowptr[N] = E;
}

extern "C" void kernel_launch(void* const* d_in, const int* in_sizes, int n_in,
                              void* d_out, int out_size, void* d_ws, size_t ws_size,
                              hipStream_t stream) {
    const float* x    = (const float*)d_in[0];
    const int*   ei   = (const int*)d_in[1];
    const float* W    = (const float*)d_in[2];
    const float* bias = (const float*)d_in[3];
    float*       out  = (float*)d_out;

    const int N = in_sizes[0] / 128;
    const int E = in_sizes[1] / 2;
    const int* row = ei;
    const int* col = ei + E;

    const int nbuck = (N + NPB - 1) >> BSHIFT;
    const int M     = nbuck * NBLK_P;           // cnt/off entries
    const int chunk = (E + NBLK_P - 1) / NBLK_P;
    const int NBm   = (M + SCAN_B - 1) / SCAN_B;

    auto al = [](size_t v) { return (v + 511) & ~(size_t)511; };
    // fast-path layout
    size_t o_cnt    = 0;
    size_t o_off    = al(o_cnt + (size_t)M * 4);
    size_t o_bsum   = al(o_off + (size_t)M * 4);
    size_t o_rowptr = al(o_bsum + 4096 * 4);
    size_t o_dis    = al(o_rowptr + ((size_t)N + 1) * 4);
    size_t o_csr    = al(o_dis + (size_t)N * 4);
    size_t o_part   = al(o_csr + (size_t)E * 4);
    size_t o_sup    = al(o_part + (size_t)E * 8);
    size_t need     = o_sup + (size_t)N * 512;

    char* ws = (char*)d_ws;

    if (ws_size >= need && nbuck <= 256 && NBm <= 1024) {
        int*   cnt    = (int*)(ws + o_cnt);
        int*   off    = (int*)(ws + o_off);
        int*   bsum   = (int*)(ws + o_bsum);
        int*   rowptr = (int*)(ws + o_rowptr);
        float* dis    = (float*)(ws + o_dis);
        int*   csr    = (int*)(ws + o_csr);
        int2*  part   = (int2*)(ws + o_part);
        float* sup    = (float*)(ws + o_sup);

        gemm_kernel<<<(N + GB_M - 1) / GB_M, 256, 0, stream>>>(x, W, sup, N);

        p1_count<<<NBLK_P, 256, 0, stream>>>(row, cnt, E, chunk, nbuck);
        scan_block_kernel<<<NBm, SCAN_B, 0, stream>>>(cnt, off, bsum, M);
        scan_bsum_kernel<<<1, 1024, 0, stream>>>(bsum, NBm);
        scan_add_kernel<<<NBm, SCAN_B, 0, stream>>>(off, bsum, M);
        p2_scatter<<<NBLK_P, 256, 0, stream>>>(row, col, off, part, E, chunk, nbuck);
        p3_build<<<nbuck, 256, 0, stream>>>(part, off, rowptr, dis, csr, N, E, nbuck);

        long long gthreads = (long long)N * 64;
        gather_kernel<<<(int)((gthreads + 255) / 256), 256, 0, stream>>>(
            csr, rowptr, dis, sup, bias, out, N);
    } else {
        // fallback: round-2 path (global-atomic CSR build)
        size_t f_degi   = 0;
        size_t f_dis    = al(f_degi + (size_t)N * 4);
        size_t f_start  = al(f_dis + (size_t)N * 4);
        size_t f_rowptr = al(f_start + (size_t)N * 4);
        size_t f_bsum   = al(f_rowptr + ((size_t)N + 1) * 4);
        size_t f_csr    = al(f_bsum + 4096 * 4);
        size_t f_sup    = al(f_csr + (size_t)E * 4);

        int*   degi   = (int*)(ws + f_degi);
        float* dis    = (float*)(ws + f_dis);
        int*   startv = (int*)(ws + f_start);
        int*   rowptr = (int*)(ws + f_rowptr);
        int*   bsum   = (int*)(ws + f_bsum);
        int*   csr    = (int*)(ws + f_csr);
        float* sup    = (float*)(ws + f_sup);
        const int NBn = (N + SCAN_B - 1) / SCAN_B;

        hipMemsetAsync(degi, 0, (size_t)N * 4, stream);
        gemm_kernel<<<(N + GB_M - 1) / GB_M, 256, 0, stream>>>(x, W, sup, N);
        deg_i_kernel<<<(E + 255) / 256, 256, 0, stream>>>(row, degi, E);
        scan_block_kernel<<<NBn, SCAN_B, 0, stream>>>(degi, startv, bsum, N);
        scan_bsum_kernel<<<1, 1024, 0, stream>>>(bsum, NBn);
        scan_add_kernel<<<NBn, SCAN_B, 0, stream>>>(startv, bsum, N);
        rowptr_from_start_kernel<<<NBn, SCAN_B, 0, stream>>>(degi, startv, rowptr, N, E);
        rsqrt_i_kernel<<<NBn, SCAN_B, 0, stream>>>(degi, dis, N);
        fill_kernel<<<(E + 255) / 256, 256, 0, stream>>>(row, col, startv, csr, E);
        long long gthreads = (long long)N * 64;
        gather_kernel<<<(int)((gthreads + 255) / 256), 256, 0, stream>>>(
            csr, rowptr, dis, sup, bias, out, N);
    }
}

// Round 4
// 185.518 us; speedup vs baseline: 8.2430x; 1.2114x over previous
//
#include <hip/hip_runtime.h>
#include <hip/hip_bf16.h>

// GCNConv: out = scatter_add_row( norm[e] * (x@W)[col[e]] ) + bias
// Round 4: bf16 support storage (halves the gather's random-read bytes),
// packed uint32 partition records (halves p2/p3 traffic).

#define SCAN_B 256
#define NBLK_P 256      // partition blocks
#define BSHIFT 9        // 512 nodes per bucket
#define NPB    512      // nodes per bucket

__device__ __forceinline__ uint32_t f2bf_rne(float f) {
    uint32_t u = __float_as_uint(f);
    return (u + 0x7fffu + ((u >> 16) & 1u)) >> 16;
}
__device__ __forceinline__ float bf_lo(uint32_t u) { return __uint_as_float(u << 16); }
__device__ __forceinline__ float bf_hi(uint32_t u) { return __uint_as_float(u & 0xffff0000u); }

// ---------------- P1: per-block bucket histogram ----------------
__global__ __launch_bounds__(256) void p1_count(const int* __restrict__ row,
                                                int* __restrict__ cnt,
                                                int E, int chunk, int nbuck) {
    __shared__ int h[256];
    const int blk = blockIdx.x, t = threadIdx.x;
    for (int i = t; i < nbuck; i += 256) h[i] = 0;
    __syncthreads();
    int lo = blk * chunk, hi = min(E, lo + chunk);
    for (int e = lo + t; e < hi; e += 256) atomicAdd(&h[row[e] >> BSHIFT], 1);
    __syncthreads();
    for (int b = t; b < nbuck; b += 256) cnt[b * NBLK_P + blk] = h[b];
}

// ---------------- scan (3-step, exclusive) ----------------
__global__ void scan_block_kernel(const int* __restrict__ in, int* __restrict__ outp,
                                  int* __restrict__ bsum, int M) {
    __shared__ int s[SCAN_B];
    int t = threadIdx.x;
    int g = blockIdx.x * SCAN_B + t;
    int v = (g < M) ? in[g] : 0;
    s[t] = v;
    __syncthreads();
#pragma unroll
    for (int off = 1; off < SCAN_B; off <<= 1) {
        int u = (t >= off) ? s[t - off] : 0;
        __syncthreads();
        s[t] += u;
        __syncthreads();
    }
    if (g < M) outp[g] = s[t] - v;
    if (t == SCAN_B - 1) bsum[blockIdx.x] = s[t];
}

__global__ void scan_bsum_kernel(int* __restrict__ bsum, int NB) {
    __shared__ int s[1024];
    int t = threadIdx.x;
    int v = (t < NB) ? bsum[t] : 0;
    s[t] = v;
    __syncthreads();
#pragma unroll
    for (int off = 1; off < 1024; off <<= 1) {
        int u = (t >= off) ? s[t - off] : 0;
        __syncthreads();
        s[t] += u;
        __syncthreads();
    }
    if (t < NB) bsum[t] = s[t] - v;
}

__global__ void scan_add_kernel(int* __restrict__ outp, const int* __restrict__ bsum, int M) {
    int g = blockIdx.x * blockDim.x + threadIdx.x;
    if (g < M) outp[g] += bsum[g >> 8];
}

// ---------------- P2: partition edges into bucket-ordered packed records ----
// record = (row & 511) << 17 | col   (needs col < 2^17)
__global__ __launch_bounds__(256) void p2_scatter(const int* __restrict__ row,
                                                  const int* __restrict__ col,
                                                  const int* __restrict__ off,
                                                  uint32_t* __restrict__ part,
                                                  int E, int chunk, int nbuck) {
    __shared__ int cur[256];
    const int blk = blockIdx.x, t = threadIdx.x;
    for (int b = t; b < nbuck; b += 256) cur[b] = off[b * NBLK_P + blk];
    __syncthreads();
    int lo = blk * chunk, hi = min(E, lo + chunk);
    for (int e = lo + t; e < hi; e += 256) {
        int r = row[e], c = col[e];
        int pos = atomicAdd(&cur[r >> BSHIFT], 1);
        part[pos] = ((uint32_t)(r & (NPB - 1)) << 17) | (uint32_t)c;
    }
}

// ---------------- P3: per-bucket CSR build (one block per bucket) ----------------
__global__ __launch_bounds__(256) void p3_build(const uint32_t* __restrict__ part,
                                                const int* __restrict__ off,
                                                int* __restrict__ rowptr,
                                                float* __restrict__ dis,
                                                int* __restrict__ csr,
                                                int N, int E, int nbuck) {
    __shared__ int hist[NPB];
    __shared__ int lstart[NPB];
    __shared__ int s[256];
    const int b = blockIdx.x, t = threadIdx.x;
    const int base_node = b << BSHIFT;
    const int csr_base  = off[b * NBLK_P];
    const int end_b     = (b == nbuck - 1) ? E : off[(b + 1) * NBLK_P];

    for (int i = t; i < NPB; i += 256) hist[i] = 0;
    __syncthreads();
    for (int e = csr_base + t; e < end_b; e += 256)
        atomicAdd(&hist[part[e] >> 17], 1);
    __syncthreads();

    // exclusive scan of hist[0..511] with 256 threads
    int a0 = hist[2 * t], a1 = hist[2 * t + 1];
    s[t] = a0 + a1;
    __syncthreads();
    int v = s[t];
#pragma unroll
    for (int o = 1; o < 256; o <<= 1) {
        int u = (t >= o) ? s[t - o] : 0;
        __syncthreads();
        s[t] += u;
        __syncthreads();
    }
    int ex = s[t] - v;
    lstart[2 * t]     = ex;
    lstart[2 * t + 1] = ex + a0;
    __syncthreads();

    for (int i = t; i < NPB; i += 256) {
        int node = base_node + i;
        if (node < N) {
            rowptr[node] = csr_base + lstart[i];
            dis[node]    = rsqrtf((float)hist[i]);
        }
    }
    __syncthreads();
    for (int i = t; i < NPB; i += 256) hist[i] = lstart[i];
    __syncthreads();
    for (int e = csr_base + t; e < end_b; e += 256) {
        uint32_t p = part[e];
        int pos = csr_base + atomicAdd(&hist[p >> 17], 1);
        csr[pos] = (int)(p & 0x1FFFFu);
    }
    if (b == 0 && t == 0) rowptr[N] = E;
}

// ---------------- GEMM: S[N,128](bf16) = X[N,128] @ W[128,128] ----------------
#define GB_M 64
#define GB_KC 32
__global__ __launch_bounds__(256) void gemm_kernel(const float* __restrict__ X,
                                                   const float* __restrict__ W,
                                                   uint32_t* __restrict__ S, int N) {
    __shared__ float sXT[GB_KC][72];
    __shared__ float sW[GB_KC][128];
    const int t  = threadIdx.x;
    const int tx = t & 15;
    const int ty = t >> 4;
    const int bm = blockIdx.x * GB_M;

    float acc[4][8];
#pragma unroll
    for (int i = 0; i < 4; ++i)
#pragma unroll
        for (int j = 0; j < 8; ++j) acc[i][j] = 0.f;

    const int sr = t >> 2;
    const int sc = (t & 3) << 2;

    for (int k0 = 0; k0 < 128; k0 += GB_KC) {
#pragma unroll
        for (int h = 0; h < 2; ++h) {
            int kk = sc + h * 16;
            int gr = bm + sr;
            float4 v = make_float4(0.f, 0.f, 0.f, 0.f);
            if (gr < N) v = *(const float4*)(X + (size_t)gr * 128 + k0 + kk);
            sXT[kk + 0][sr] = v.x;
            sXT[kk + 1][sr] = v.y;
            sXT[kk + 2][sr] = v.z;
            sXT[kk + 3][sr] = v.w;
        }
#pragma unroll
        for (int h = 0; h < 4; ++h) {
            int idx = t + h * 256;
            int wk  = idx >> 5;
            int wo  = (idx & 31) << 2;
            *(float4*)&sW[wk][wo] = *(const float4*)(W + (size_t)(k0 + wk) * 128 + wo);
        }
        __syncthreads();
#pragma unroll
        for (int k = 0; k < GB_KC; ++k) {
            float4 a  = *(const float4*)&sXT[k][ty * 4];
            float4 b0 = *(const float4*)&sW[k][tx * 4];
            float4 b1 = *(const float4*)&sW[k][64 + tx * 4];
            float av[4] = {a.x, a.y, a.z, a.w};
            float bv[8] = {b0.x, b0.y, b0.z, b0.w, b1.x, b1.y, b1.z, b1.w};
#pragma unroll
            for (int i = 0; i < 4; ++i)
#pragma unroll
                for (int j = 0; j < 8; ++j) acc[i][j] += av[i] * bv[j];
        }
        __syncthreads();
    }
    // epilogue: bf16 pack. Channels tx*4..tx*4+3 -> pair idx tx*2,tx*2+1;
    // channels 64+tx*4.. -> pair idx 32+tx*2, 33+tx*2. Row stride = 64 uints.
#pragma unroll
    for (int i = 0; i < 4; ++i) {
        int gr = bm + ty * 4 + i;
        if (gr < N) {
            uint32_t p0 = f2bf_rne(acc[i][0]) | (f2bf_rne(acc[i][1]) << 16);
            uint32_t p1 = f2bf_rne(acc[i][2]) | (f2bf_rne(acc[i][3]) << 16);
            uint32_t p2 = f2bf_rne(acc[i][4]) | (f2bf_rne(acc[i][5]) << 16);
            uint32_t p3 = f2bf_rne(acc[i][6]) | (f2bf_rne(acc[i][7]) << 16);
            *(uint2*)(S + (size_t)gr * 64 + tx * 2)      = make_uint2(p0, p1);
            *(uint2*)(S + (size_t)gr * 64 + 32 + tx * 2) = make_uint2(p2, p3);
        }
    }
}

// ---------------- gather: one wave per node, one bf16-pair (4B) per lane ------
__global__ __launch_bounds__(256) void gather_kernel(const int* __restrict__ csr,
                                                     const int* __restrict__ rowptr,
                                                     const float* __restrict__ dis,
                                                     const uint32_t* __restrict__ sup,
                                                     const float* __restrict__ bias,
                                                     float* __restrict__ out, int N) {
    int wid  = (blockIdx.x * blockDim.x + threadIdx.x) >> 6;
    int lane = threadIdx.x & 63;
    if (wid >= N) return;
    int begin = rowptr[wid];
    int end   = rowptr[wid + 1];
    float dr  = dis[wid];
    float2 acc = *(const float2*)(bias + lane * 2);

    int j = begin;
    for (; j + 3 < end; j += 4) {
        int c0 = csr[j], c1 = csr[j + 1], c2 = csr[j + 2], c3 = csr[j + 3];
        float n0 = dr * dis[c0], n1 = dr * dis[c1], n2 = dr * dis[c2], n3 = dr * dis[c3];
        uint32_t u0 = sup[(size_t)c0 * 64 + lane];
        uint32_t u1 = sup[(size_t)c1 * 64 + lane];
        uint32_t u2 = sup[(size_t)c2 * 64 + lane];
        uint32_t u3 = sup[(size_t)c3 * 64 + lane];
        acc.x += n0 * bf_lo(u0) + n1 * bf_lo(u1) + n2 * bf_lo(u2) + n3 * bf_lo(u3);
        acc.y += n0 * bf_hi(u0) + n1 * bf_hi(u1) + n2 * bf_hi(u2) + n3 * bf_hi(u3);
    }
    for (; j < end; ++j) {
        int c = csr[j];
        float nrm = dr * dis[c];
        uint32_t u = sup[(size_t)c * 64 + lane];
        acc.x += nrm * bf_lo(u);
        acc.y += nrm * bf_hi(u);
    }
    *(float2*)(out + (size_t)wid * 128 + lane * 2) = acc;
}

// ---------------- round-2 style fallback kernels ----------------
__global__ void deg_i_kernel(const int* __restrict__ row, int* __restrict__ degi, int E) {
    int g = blockIdx.x * blockDim.x + threadIdx.x;
    if (g < E) atomicAdd(&degi[row[g]], 1);
}
__global__ void rsqrt_i_kernel(const int* __restrict__ degi, float* __restrict__ dis, int N) {
    int g = blockIdx.x * blockDim.x + threadIdx.x;
    if (g < N) dis[g] = rsqrtf((float)degi[g]);
}
__global__ void fill_kernel(const int* __restrict__ row, const int* __restrict__ col,
                            int* __restrict__ start, int* __restrict__ csr, int E) {
    int e = blockIdx.x * blockDim.x + threadIdx.x;
    if (e < E) {
        int pos = atomicAdd(&start[row[e]], 1);
        csr[pos] = col[e];
    }
}
__global__ void rowptr_from_start_kernel(const int* __restrict__ startv,
                                         int* __restrict__ rowptr, int N, int E) {
    int g = blockIdx.x * blockDim.x + threadIdx.x;
    if (g < N) rowptr[g] = startv[g];
    if (g == 0) rowptr[N] = E;
}

extern "C" void kernel_launch(void* const* d_in, const int* in_sizes, int n_in,
                              void* d_out, int out_size, void* d_ws, size_t ws_size,
                              hipStream_t stream) {
    const float* x    = (const float*)d_in[0];
    const int*   ei   = (const int*)d_in[1];
    const float* W    = (const float*)d_in[2];
    const float* bias = (const float*)d_in[3];
    float*       out  = (float*)d_out;

    const int N = in_sizes[0] / 128;
    const int E = in_sizes[1] / 2;
    const int* row = ei;
    const int* col = ei + E;

    const int nbuck = (N + NPB - 1) >> BSHIFT;
    const int M     = nbuck * NBLK_P;
    const int chunk = (E + NBLK_P - 1) / NBLK_P;
    const int NBm   = (M + SCAN_B - 1) / SCAN_B;

    auto al = [](size_t v) { return (v + 511) & ~(size_t)511; };
    size_t o_cnt    = 0;
    size_t o_off    = al(o_cnt + (size_t)M * 4);
    size_t o_bsum   = al(o_off + (size_t)M * 4);
    size_t o_rowptr = al(o_bsum + 4096 * 4);
    size_t o_dis    = al(o_rowptr + ((size_t)N + 1) * 4);
    size_t o_csr    = al(o_dis + (size_t)N * 4);
    size_t o_part   = al(o_csr + (size_t)E * 4);
    size_t o_sup    = al(o_part + (size_t)E * 4);
    size_t need     = o_sup + (size_t)N * 256;   // bf16 support

    char* ws = (char*)d_ws;

    if (ws_size >= need && nbuck <= 256 && NBm <= 1024 && N <= (1 << 17)) {
        int*      cnt    = (int*)(ws + o_cnt);
        int*      off    = (int*)(ws + o_off);
        int*      bsum   = (int*)(ws + o_bsum);
        int*      rowptr = (int*)(ws + o_rowptr);
        float*    dis    = (float*)(ws + o_dis);
        int*      csr    = (int*)(ws + o_csr);
        uint32_t* part   = (uint32_t*)(ws + o_part);
        uint32_t* sup    = (uint32_t*)(ws + o_sup);

        gemm_kernel<<<(N + GB_M - 1) / GB_M, 256, 0, stream>>>(x, W, sup, N);

        p1_count<<<NBLK_P, 256, 0, stream>>>(row, cnt, E, chunk, nbuck);
        scan_block_kernel<<<NBm, SCAN_B, 0, stream>>>(cnt, off, bsum, M);
        scan_bsum_kernel<<<1, 1024, 0, stream>>>(bsum, NBm);
        scan_add_kernel<<<NBm, SCAN_B, 0, stream>>>(off, bsum, M);
        p2_scatter<<<NBLK_P, 256, 0, stream>>>(row, col, off, part, E, chunk, nbuck);
        p3_build<<<nbuck, 256, 0, stream>>>(part, off, rowptr, dis, csr, N, E, nbuck);

        long long gthreads = (long long)N * 64;
        gather_kernel<<<(int)((gthreads + 255) / 256), 256, 0, stream>>>(
            csr, rowptr, dis, sup, bias, out, N);
    } else {
        // fallback: global-atomic CSR build + same bf16 gather
        size_t f_degi   = 0;
        size_t f_dis    = al(f_degi + (size_t)N * 4);
        size_t f_start  = al(f_dis + (size_t)N * 4);
        size_t f_rowptr = al(f_start + (size_t)N * 4);
        size_t f_bsum   = al(f_rowptr + ((size_t)N + 1) * 4);
        size_t f_csr    = al(f_bsum + 4096 * 4);
        size_t f_sup    = al(f_csr + (size_t)E * 4);

        int*      degi   = (int*)(ws + f_degi);
        float*    dis    = (float*)(ws + f_dis);
        int*      startv = (int*)(ws + f_start);
        int*      rowptr = (int*)(ws + f_rowptr);
        int*      bsum   = (int*)(ws + f_bsum);
        int*      csr    = (int*)(ws + f_csr);
        uint32_t* sup    = (uint32_t*)(ws + f_sup);
        const int NBn = (N + SCAN_B - 1) / SCAN_B;

        hipMemsetAsync(degi, 0, (size_t)N * 4, stream);
        gemm_kernel<<<(N + GB_M - 1) / GB_M, 256, 0, stream>>>(x, W, sup, N);
        deg_i_kernel<<<(E + 255) / 256, 256, 0, stream>>>(row, degi, E);
        scan_block_kernel<<<NBn, SCAN_B, 0, stream>>>(degi, startv, bsum, N);
        scan_bsum_kernel<<<1, 1024, 0, stream>>>(bsum, NBn);
        scan_add_kernel<<<NBn, SCAN_B, 0, stream>>>(startv, bsum, N);
        rowptr_from_start_kernel<<<NBn, SCAN_B, 0, stream>>>(startv, rowptr, N, E);
        rsqrt_i_kernel<<<NBn, SCAN_B, 0, stream>>>(degi, dis, N);
        fill_kernel<<<(E + 255) / 256, 256, 0, stream>>>(row, col, startv, csr, E);
        long long gthreads = (long long)N * 64;
        gather_kernel<<<(int)((gthreads + 255) / 256), 256, 0, stream>>>(
            csr, rowptr, dis, sup, bias, out, N);
    }
}

// Round 5
// 164.517 us; speedup vs baseline: 9.2952x; 1.1277x over previous
//
#include <hip/hip_runtime.h>
#include <hip/hip_bf16.h>

// GCNConv: out = scatter_add_row( norm[e] * (x@W)[col[e]] ) + bias
// Round 5: MFMA bf16 GEMM (LDS-free, A from global, B from pre-transposed
// bf16 W). sup uint32 pair layout = (ch, ch+64) to avoid epilogue repack.

#define SCAN_B 256
#define NBLK_P 256      // partition blocks
#define BSHIFT 9        // 512 nodes per bucket
#define NPB    512      // nodes per bucket

typedef __attribute__((ext_vector_type(8))) short bf16x8;
typedef __attribute__((ext_vector_type(4))) float f32x4;

__device__ __forceinline__ uint32_t f2bf_rne(float f) {
    uint32_t u = __float_as_uint(f);
    return (u + 0x7fffu + ((u >> 16) & 1u)) >> 16;
}
__device__ __forceinline__ float bf_lo(uint32_t u) { return __uint_as_float(u << 16); }
__device__ __forceinline__ float bf_hi(uint32_t u) { return __uint_as_float(u & 0xffff0000u); }

__device__ __forceinline__ bf16x8 pack8(float4 lo, float4 hi) {
    union { bf16x8 v; ushort u[8]; } r;
    r.u[0] = (ushort)f2bf_rne(lo.x);
    r.u[1] = (ushort)f2bf_rne(lo.y);
    r.u[2] = (ushort)f2bf_rne(lo.z);
    r.u[3] = (ushort)f2bf_rne(lo.w);
    r.u[4] = (ushort)f2bf_rne(hi.x);
    r.u[5] = (ushort)f2bf_rne(hi.y);
    r.u[6] = (ushort)f2bf_rne(hi.z);
    r.u[7] = (ushort)f2bf_rne(hi.w);
    return r.v;
}

// ---------------- W -> Wt bf16 transposed [n][k] ----------------
__global__ void wconv_kernel(const float* __restrict__ W, ushort* __restrict__ Wt) {
    int t = blockIdx.x * blockDim.x + threadIdx.x;   // 0..16383
    int n = t >> 7, k = t & 127;
    Wt[n * 128 + k] = (ushort)f2bf_rne(W[k * 128 + n]);
}

// ---------------- MFMA GEMM: S[N,128](bf16 pairs ch,ch+64) = X @ W ----------
// Block = 256 thr = 4 waves; wave owns 32 rows (2 M-frags); block = 128 rows.
__global__ __launch_bounds__(256) void mfma_gemm(const float* __restrict__ X,
                                                 const ushort* __restrict__ Wt,
                                                 uint32_t* __restrict__ S, int N) {
    const int wave = threadIdx.x >> 6;
    const int lane = threadIdx.x & 63;
    const int c16  = lane & 15;
    const int kg   = lane >> 4;
    const int row0 = blockIdx.x * 128 + wave * 32;

    int rA0 = row0 + c16;
    int rA1 = row0 + 16 + c16;
    if (rA0 >= N) rA0 = N - 1;
    if (rA1 >= N) rA1 = N - 1;

    f32x4 acc[2][8];
#pragma unroll
    for (int m = 0; m < 2; ++m)
#pragma unroll
        for (int cb = 0; cb < 8; ++cb) acc[m][cb] = (f32x4){0.f, 0.f, 0.f, 0.f};

    const float*  xa0 = X + (size_t)rA0 * 128 + kg * 8;
    const float*  xa1 = X + (size_t)rA1 * 128 + kg * 8;
    const ushort* wb  = Wt + kg * 8 + c16 * 128;

#pragma unroll
    for (int kk = 0; kk < 4; ++kk) {
        float4 a0lo = *(const float4*)(xa0 + kk * 32);
        float4 a0hi = *(const float4*)(xa0 + kk * 32 + 4);
        float4 a1lo = *(const float4*)(xa1 + kk * 32);
        float4 a1hi = *(const float4*)(xa1 + kk * 32 + 4);
        bf16x8 A0 = pack8(a0lo, a0hi);
        bf16x8 A1 = pack8(a1lo, a1hi);
#pragma unroll
        for (int cb = 0; cb < 8; ++cb) {
            bf16x8 B = *(const bf16x8*)(wb + (size_t)cb * 16 * 128 + kk * 32);
            acc[0][cb] = __builtin_amdgcn_mfma_f32_16x16x32_bf16(A0, B, acc[0][cb], 0, 0, 0);
            acc[1][cb] = __builtin_amdgcn_mfma_f32_16x16x32_bf16(A1, B, acc[1][cb], 0, 0, 0);
        }
    }
    // C/D: col = c16 (within frag), row = kg*4 + i. Pair (ch n, ch n+64):
    // acc[m][cb] (n=cb*16+c16) with acc[m][cb+4] (n+64).
#pragma unroll
    for (int m = 0; m < 2; ++m) {
#pragma unroll
        for (int i = 0; i < 4; ++i) {
            int gr = row0 + m * 16 + kg * 4 + i;
            if (gr < N) {
#pragma unroll
                for (int cb = 0; cb < 4; ++cb) {
                    uint32_t p = f2bf_rne(acc[m][cb][i]) |
                                 (f2bf_rne(acc[m][cb + 4][i]) << 16);
                    S[(size_t)gr * 64 + cb * 16 + c16] = p;
                }
            }
        }
    }
}

// ---------------- P1: per-block bucket histogram ----------------
__global__ __launch_bounds__(256) void p1_count(const int* __restrict__ row,
                                                int* __restrict__ cnt,
                                                int E, int chunk, int nbuck) {
    __shared__ int h[256];
    const int blk = blockIdx.x, t = threadIdx.x;
    for (int i = t; i < nbuck; i += 256) h[i] = 0;
    __syncthreads();
    int lo = blk * chunk, hi = min(E, lo + chunk);
    for (int e = lo + t; e < hi; e += 256) atomicAdd(&h[row[e] >> BSHIFT], 1);
    __syncthreads();
    for (int b = t; b < nbuck; b += 256) cnt[b * NBLK_P + blk] = h[b];
}

// ---------------- scan (3-step, exclusive) ----------------
__global__ void scan_block_kernel(const int* __restrict__ in, int* __restrict__ outp,
                                  int* __restrict__ bsum, int M) {
    __shared__ int s[SCAN_B];
    int t = threadIdx.x;
    int g = blockIdx.x * SCAN_B + t;
    int v = (g < M) ? in[g] : 0;
    s[t] = v;
    __syncthreads();
#pragma unroll
    for (int off = 1; off < SCAN_B; off <<= 1) {
        int u = (t >= off) ? s[t - off] : 0;
        __syncthreads();
        s[t] += u;
        __syncthreads();
    }
    if (g < M) outp[g] = s[t] - v;
    if (t == SCAN_B - 1) bsum[blockIdx.x] = s[t];
}

__global__ void scan_bsum_kernel(int* __restrict__ bsum, int NB) {
    __shared__ int s[1024];
    int t = threadIdx.x;
    int v = (t < NB) ? bsum[t] : 0;
    s[t] = v;
    __syncthreads();
#pragma unroll
    for (int off = 1; off < 1024; off <<= 1) {
        int u = (t >= off) ? s[t - off] : 0;
        __syncthreads();
        s[t] += u;
        __syncthreads();
    }
    if (t < NB) bsum[t] = s[t] - v;
}

__global__ void scan_add_kernel(int* __restrict__ outp, const int* __restrict__ bsum, int M) {
    int g = blockIdx.x * blockDim.x + threadIdx.x;
    if (g < M) outp[g] += bsum[g >> 8];
}

// ---------------- P2: partition edges into bucket-ordered packed records ----
__global__ __launch_bounds__(256) void p2_scatter(const int* __restrict__ row,
                                                  const int* __restrict__ col,
                                                  const int* __restrict__ off,
                                                  uint32_t* __restrict__ part,
                                                  int E, int chunk, int nbuck) {
    __shared__ int cur[256];
    const int blk = blockIdx.x, t = threadIdx.x;
    for (int b = t; b < nbuck; b += 256) cur[b] = off[b * NBLK_P + blk];
    __syncthreads();
    int lo = blk * chunk, hi = min(E, lo + chunk);
    for (int e = lo + t; e < hi; e += 256) {
        int r = row[e], c = col[e];
        int pos = atomicAdd(&cur[r >> BSHIFT], 1);
        part[pos] = ((uint32_t)(r & (NPB - 1)) << 17) | (uint32_t)c;
    }
}

// ---------------- P3: per-bucket CSR build (one block per bucket) ----------------
__global__ __launch_bounds__(256) void p3_build(const uint32_t* __restrict__ part,
                                                const int* __restrict__ off,
                                                int* __restrict__ rowptr,
                                                float* __restrict__ dis,
                                                int* __restrict__ csr,
                                                int N, int E, int nbuck) {
    __shared__ int hist[NPB];
    __shared__ int lstart[NPB];
    __shared__ int s[256];
    const int b = blockIdx.x, t = threadIdx.x;
    const int base_node = b << BSHIFT;
    const int csr_base  = off[b * NBLK_P];
    const int end_b     = (b == nbuck - 1) ? E : off[(b + 1) * NBLK_P];

    for (int i = t; i < NPB; i += 256) hist[i] = 0;
    __syncthreads();
    for (int e = csr_base + t; e < end_b; e += 256)
        atomicAdd(&hist[part[e] >> 17], 1);
    __syncthreads();

    int a0 = hist[2 * t], a1 = hist[2 * t + 1];
    s[t] = a0 + a1;
    __syncthreads();
    int v = s[t];
#pragma unroll
    for (int o = 1; o < 256; o <<= 1) {
        int u = (t >= o) ? s[t - o] : 0;
        __syncthreads();
        s[t] += u;
        __syncthreads();
    }
    int ex = s[t] - v;
    lstart[2 * t]     = ex;
    lstart[2 * t + 1] = ex + a0;
    __syncthreads();

    for (int i = t; i < NPB; i += 256) {
        int node = base_node + i;
        if (node < N) {
            rowptr[node] = csr_base + lstart[i];
            dis[node]    = rsqrtf((float)hist[i]);
        }
    }
    __syncthreads();
    for (int i = t; i < NPB; i += 256) hist[i] = lstart[i];
    __syncthreads();
    for (int e = csr_base + t; e < end_b; e += 256) {
        uint32_t p = part[e];
        int pos = csr_base + atomicAdd(&hist[p >> 17], 1);
        csr[pos] = (int)(p & 0x1FFFFu);
    }
    if (b == 0 && t == 0) rowptr[N] = E;
}

// ---------------- gather: one wave per node; lane handles (ch, ch+64) --------
__global__ __launch_bounds__(256) void gather_kernel(const int* __restrict__ csr,
                                                     const int* __restrict__ rowptr,
                                                     const float* __restrict__ dis,
                                                     const uint32_t* __restrict__ sup,
                                                     const float* __restrict__ bias,
                                                     float* __restrict__ out, int N) {
    int wid  = (blockIdx.x * blockDim.x + threadIdx.x) >> 6;
    int lane = threadIdx.x & 63;
    if (wid >= N) return;
    int begin = rowptr[wid];
    int end   = rowptr[wid + 1];
    float dr  = dis[wid];
    float2 acc;
    acc.x = bias[lane];
    acc.y = bias[64 + lane];

    int j = begin;
    for (; j + 3 < end; j += 4) {
        int c0 = csr[j], c1 = csr[j + 1], c2 = csr[j + 2], c3 = csr[j + 3];
        float n0 = dr * dis[c0], n1 = dr * dis[c1], n2 = dr * dis[c2], n3 = dr * dis[c3];
        uint32_t u0 = sup[(size_t)c0 * 64 + lane];
        uint32_t u1 = sup[(size_t)c1 * 64 + lane];
        uint32_t u2 = sup[(size_t)c2 * 64 + lane];
        uint32_t u3 = sup[(size_t)c3 * 64 + lane];
        acc.x += n0 * bf_lo(u0) + n1 * bf_lo(u1) + n2 * bf_lo(u2) + n3 * bf_lo(u3);
        acc.y += n0 * bf_hi(u0) + n1 * bf_hi(u1) + n2 * bf_hi(u2) + n3 * bf_hi(u3);
    }
    for (; j < end; ++j) {
        int c = csr[j];
        float nrm = dr * dis[c];
        uint32_t u = sup[(size_t)c * 64 + lane];
        acc.x += nrm * bf_lo(u);
        acc.y += nrm * bf_hi(u);
    }
    out[(size_t)wid * 128 + lane]      = acc.x;
    out[(size_t)wid * 128 + 64 + lane] = acc.y;
}

// ---------------- fallback fp32 GEMM (epilogue matches (ch,ch+64) pairs) -----
#define GB_M 64
#define GB_KC 32
__global__ __launch_bounds__(256) void gemm_kernel(const float* __restrict__ X,
                                                   const float* __restrict__ W,
                                                   uint32_t* __restrict__ S, int N) {
    __shared__ float sXT[GB_KC][72];
    __shared__ float sW[GB_KC][128];
    const int t  = threadIdx.x;
    const int tx = t & 15;
    const int ty = t >> 4;
    const int bm = blockIdx.x * GB_M;

    float acc[4][8];
#pragma unroll
    for (int i = 0; i < 4; ++i)
#pragma unroll
        for (int j = 0; j < 8; ++j) acc[i][j] = 0.f;

    const int sr = t >> 2;
    const int sc = (t & 3) << 2;

    for (int k0 = 0; k0 < 128; k0 += GB_KC) {
#pragma unroll
        for (int h = 0; h < 2; ++h) {
            int kk = sc + h * 16;
            int gr = bm + sr;
            float4 v = make_float4(0.f, 0.f, 0.f, 0.f);
            if (gr < N) v = *(const float4*)(X + (size_t)gr * 128 + k0 + kk);
            sXT[kk + 0][sr] = v.x;
            sXT[kk + 1][sr] = v.y;
            sXT[kk + 2][sr] = v.z;
            sXT[kk + 3][sr] = v.w;
        }
#pragma unroll
        for (int h = 0; h < 4; ++h) {
            int idx = t + h * 256;
            int wk  = idx >> 5;
            int wo  = (idx & 31) << 2;
            *(float4*)&sW[wk][wo] = *(const float4*)(W + (size_t)(k0 + wk) * 128 + wo);
        }
        __syncthreads();
#pragma unroll
        for (int k = 0; k < GB_KC; ++k) {
            float4 a  = *(const float4*)&sXT[k][ty * 4];
            float4 b0 = *(const float4*)&sW[k][tx * 4];
            float4 b1 = *(const float4*)&sW[k][64 + tx * 4];
            float av[4] = {a.x, a.y, a.z, a.w};
            float bv[8] = {b0.x, b0.y, b0.z, b0.w, b1.x, b1.y, b1.z, b1.w};
#pragma unroll
            for (int i = 0; i < 4; ++i)
#pragma unroll
                for (int j = 0; j < 8; ++j) acc[i][j] += av[i] * bv[j];
        }
        __syncthreads();
    }
#pragma unroll
    for (int i = 0; i < 4; ++i) {
        int gr = bm + ty * 4 + i;
        if (gr < N) {
            uint4 q;
            q.x = f2bf_rne(acc[i][0]) | (f2bf_rne(acc[i][4]) << 16);
            q.y = f2bf_rne(acc[i][1]) | (f2bf_rne(acc[i][5]) << 16);
            q.z = f2bf_rne(acc[i][2]) | (f2bf_rne(acc[i][6]) << 16);
            q.w = f2bf_rne(acc[i][3]) | (f2bf_rne(acc[i][7]) << 16);
            *(uint4*)(S + (size_t)gr * 64 + tx * 4) = q;
        }
    }
}

// ---------------- fallback CSR-build kernels ----------------
__global__ void deg_i_kernel(const int* __restrict__ row, int* __restrict__ degi, int E) {
    int g = blockIdx.x * blockDim.x + threadIdx.x;
    if (g < E) atomicAdd(&degi[row[g]], 1);
}
__global__ void rsqrt_i_kernel(const int* __restrict__ degi, float* __restrict__ dis, int N) {
    int g = blockIdx.x * blockDim.x + threadIdx.x;
    if (g < N) dis[g] = rsqrtf((float)degi[g]);
}
__global__ void fill_kernel(const int* __restrict__ row, const int* __restrict__ col,
                            int* __restrict__ start, int* __restrict__ csr, int E) {
    int e = blockIdx.x * blockDim.x + threadIdx.x;
    if (e < E) {
        int pos = atomicAdd(&start[row[e]], 1);
        csr[pos] = col[e];
    }
}
__global__ void rowptr_from_start_kernel(const int* __restrict__ startv,
                                         int* __restrict__ rowptr, int N, int E) {
    int g = blockIdx.x * blockDim.x + threadIdx.x;
    if (g < N) rowptr[g] = startv[g];
    if (g == 0) rowptr[N] = E;
}

extern "C" void kernel_launch(void* const* d_in, const int* in_sizes, int n_in,
                              void* d_out, int out_size, void* d_ws, size_t ws_size,
                              hipStream_t stream) {
    const float* x    = (const float*)d_in[0];
    const int*   ei   = (const int*)d_in[1];
    const float* W    = (const float*)d_in[2];
    const float* bias = (const float*)d_in[3];
    float*       out  = (float*)d_out;

    const int N = in_sizes[0] / 128;
    const int E = in_sizes[1] / 2;
    const int* row = ei;
    const int* col = ei + E;

    const int nbuck = (N + NPB - 1) >> BSHIFT;
    const int M     = nbuck * NBLK_P;
    const int chunk = (E + NBLK_P - 1) / NBLK_P;
    const int NBm   = (M + SCAN_B - 1) / SCAN_B;

    auto al = [](size_t v) { return (v + 511) & ~(size_t)511; };
    size_t o_cnt    = 0;
    size_t o_off    = al(o_cnt + (size_t)M * 4);
    size_t o_bsum   = al(o_off + (size_t)M * 4);
    size_t o_rowptr = al(o_bsum + 4096 * 4);
    size_t o_dis    = al(o_rowptr + ((size_t)N + 1) * 4);
    size_t o_csr    = al(o_dis + (size_t)N * 4);
    size_t o_part   = al(o_csr + (size_t)E * 4);
    size_t o_wt     = al(o_part + (size_t)E * 4);
    size_t o_sup    = al(o_wt + 128 * 128 * 2);
    size_t need     = o_sup + (size_t)N * 256;   // bf16 support

    char* ws = (char*)d_ws;

    if (ws_size >= need && nbuck <= 256 && NBm <= 1024 && N <= (1 << 17)) {
        int*      cnt    = (int*)(ws + o_cnt);
        int*      off    = (int*)(ws + o_off);
        int*      bsum   = (int*)(ws + o_bsum);
        int*      rowptr = (int*)(ws + o_rowptr);
        float*    dis    = (float*)(ws + o_dis);
        int*      csr    = (int*)(ws + o_csr);
        uint32_t* part   = (uint32_t*)(ws + o_part);
        ushort*   wt     = (ushort*)(ws + o_wt);
        uint32_t* sup    = (uint32_t*)(ws + o_sup);

        wconv_kernel<<<64, 256, 0, stream>>>(W, wt);
        mfma_gemm<<<(N + 127) / 128, 256, 0, stream>>>(x, wt, sup, N);

        p1_count<<<NBLK_P, 256, 0, stream>>>(row, cnt, E, chunk, nbuck);
        scan_block_kernel<<<NBm, SCAN_B, 0, stream>>>(cnt, off, bsum, M);
        scan_bsum_kernel<<<1, 1024, 0, stream>>>(bsum, NBm);
        scan_add_kernel<<<NBm, SCAN_B, 0, stream>>>(off, bsum, M);
        p2_scatter<<<NBLK_P, 256, 0, stream>>>(row, col, off, part, E, chunk, nbuck);
        p3_build<<<nbuck, 256, 0, stream>>>(part, off, rowptr, dis, csr, N, E, nbuck);

        long long gthreads = (long long)N * 64;
        gather_kernel<<<(int)((gthreads + 255) / 256), 256, 0, stream>>>(
            csr, rowptr, dis, sup, bias, out, N);
    } else {
        // fallback: global-atomic CSR build + fp32 LDS GEMM + same gather
        size_t f_degi   = 0;
        size_t f_dis    = al(f_degi + (size_t)N * 4);
        size_t f_start  = al(f_dis + (size_t)N * 4);
        size_t f_rowptr = al(f_start + (size_t)N * 4);
        size_t f_bsum   = al(f_rowptr + ((size_t)N + 1) * 4);
        size_t f_csr    = al(f_bsum + 4096 * 4);
        size_t f_sup    = al(f_csr + (size_t)E * 4);

        int*      degi   = (int*)(ws + f_degi);
        float*    dis    = (float*)(ws + f_dis);
        int*      startv = (int*)(ws + f_start);
        int*      rowptr = (int*)(ws + f_rowptr);
        int*      bsum   = (int*)(ws + f_bsum);
        int*      csr    = (int*)(ws + f_csr);
        uint32_t* sup    = (uint32_t*)(ws + f_sup);
        const int NBn = (N + SCAN_B - 1) / SCAN_B;

        hipMemsetAsync(degi, 0, (size_t)N * 4, stream);
        gemm_kernel<<<(N + GB_M - 1) / GB_M, 256, 0, stream>>>(x, W, sup, N);
        deg_i_kernel<<<(E + 255) / 256, 256, 0, stream>>>(row, degi, E);
        scan_block_kernel<<<NBn, SCAN_B, 0, stream>>>(degi, startv, bsum, N);
        scan_bsum_kernel<<<1, 1024, 0, stream>>>(bsum, NBn);
        scan_add_kernel<<<NBn, SCAN_B, 0, stream>>>(startv, bsum, N);
        rowptr_from_start_kernel<<<NBn, SCAN_B, 0, stream>>>(startv, rowptr, N, E);
        rsqrt_i_kernel<<<NBn, SCAN_B, 0, stream>>>(degi, dis, N);
        fill_kernel<<<(E + 255) / 256, 256, 0, stream>>>(row, col, startv, csr, E);
        long long gthreads = (long long)N * 64;
        gather_kernel<<<(int)((gthreads + 255) / 256), 256, 0, stream>>>(
            csr, rowptr, dis, sup, bias, out, N);
    }
}

// Round 6
// 163.698 us; speedup vs baseline: 9.3417x; 1.0050x over previous
//
#include <hip/hip_runtime.h>
#include <hip/hip_bf16.h>

// GCNConv: out = scatter_add_row( norm[e] * (x@W)[col[e]] ) + bias
// Round 6: wide gather — 4 edges per wave-VMEM instruction (uint4 per lane,
// 16 lanes per edge), shfl_xor cross-slot reduction. 4x fewer VMEM instrs.

#define SCAN_B 256
#define NBLK_P 256      // partition blocks
#define BSHIFT 9        // 512 nodes per bucket
#define NPB    512      // nodes per bucket

typedef __attribute__((ext_vector_type(8))) short bf16x8;
typedef __attribute__((ext_vector_type(4))) float f32x4;

__device__ __forceinline__ uint32_t f2bf_rne(float f) {
    uint32_t u = __float_as_uint(f);
    return (u + 0x7fffu + ((u >> 16) & 1u)) >> 16;
}
__device__ __forceinline__ float bf_lo(uint32_t u) { return __uint_as_float(u << 16); }
__device__ __forceinline__ float bf_hi(uint32_t u) { return __uint_as_float(u & 0xffff0000u); }

__device__ __forceinline__ bf16x8 pack8(float4 lo, float4 hi) {
    union { bf16x8 v; ushort u[8]; } r;
    r.u[0] = (ushort)f2bf_rne(lo.x);
    r.u[1] = (ushort)f2bf_rne(lo.y);
    r.u[2] = (ushort)f2bf_rne(lo.z);
    r.u[3] = (ushort)f2bf_rne(lo.w);
    r.u[4] = (ushort)f2bf_rne(hi.x);
    r.u[5] = (ushort)f2bf_rne(hi.y);
    r.u[6] = (ushort)f2bf_rne(hi.z);
    r.u[7] = (ushort)f2bf_rne(hi.w);
    return r.v;
}

// ---------------- W -> Wt bf16 transposed [n][k] ----------------
__global__ void wconv_kernel(const float* __restrict__ W, ushort* __restrict__ Wt) {
    int t = blockIdx.x * blockDim.x + threadIdx.x;   // 0..16383
    int n = t >> 7, k = t & 127;
    Wt[n * 128 + k] = (ushort)f2bf_rne(W[k * 128 + n]);
}

// ---------------- MFMA GEMM: S[N,128](bf16 pairs ch,ch+64) = X @ W ----------
__global__ __launch_bounds__(256) void mfma_gemm(const float* __restrict__ X,
                                                 const ushort* __restrict__ Wt,
                                                 uint32_t* __restrict__ S, int N) {
    const int wave = threadIdx.x >> 6;
    const int lane = threadIdx.x & 63;
    const int c16  = lane & 15;
    const int kg   = lane >> 4;
    const int row0 = blockIdx.x * 128 + wave * 32;

    int rA0 = row0 + c16;
    int rA1 = row0 + 16 + c16;
    if (rA0 >= N) rA0 = N - 1;
    if (rA1 >= N) rA1 = N - 1;

    f32x4 acc[2][8];
#pragma unroll
    for (int m = 0; m < 2; ++m)
#pragma unroll
        for (int cb = 0; cb < 8; ++cb) acc[m][cb] = (f32x4){0.f, 0.f, 0.f, 0.f};

    const float*  xa0 = X + (size_t)rA0 * 128 + kg * 8;
    const float*  xa1 = X + (size_t)rA1 * 128 + kg * 8;
    const ushort* wb  = Wt + kg * 8 + c16 * 128;

#pragma unroll
    for (int kk = 0; kk < 4; ++kk) {
        float4 a0lo = *(const float4*)(xa0 + kk * 32);
        float4 a0hi = *(const float4*)(xa0 + kk * 32 + 4);
        float4 a1lo = *(const float4*)(xa1 + kk * 32);
        float4 a1hi = *(const float4*)(xa1 + kk * 32 + 4);
        bf16x8 A0 = pack8(a0lo, a0hi);
        bf16x8 A1 = pack8(a1lo, a1hi);
#pragma unroll
        for (int cb = 0; cb < 8; ++cb) {
            bf16x8 B = *(const bf16x8*)(wb + (size_t)cb * 16 * 128 + kk * 32);
            acc[0][cb] = __builtin_amdgcn_mfma_f32_16x16x32_bf16(A0, B, acc[0][cb], 0, 0, 0);
            acc[1][cb] = __builtin_amdgcn_mfma_f32_16x16x32_bf16(A1, B, acc[1][cb], 0, 0, 0);
        }
    }
#pragma unroll
    for (int m = 0; m < 2; ++m) {
#pragma unroll
        for (int i = 0; i < 4; ++i) {
            int gr = row0 + m * 16 + kg * 4 + i;
            if (gr < N) {
#pragma unroll
                for (int cb = 0; cb < 4; ++cb) {
                    uint32_t p = f2bf_rne(acc[m][cb][i]) |
                                 (f2bf_rne(acc[m][cb + 4][i]) << 16);
                    S[(size_t)gr * 64 + cb * 16 + c16] = p;
                }
            }
        }
    }
}

// ---------------- P1: per-block bucket histogram ----------------
__global__ __launch_bounds__(256) void p1_count(const int* __restrict__ row,
                                                int* __restrict__ cnt,
                                                int E, int chunk, int nbuck) {
    __shared__ int h[256];
    const int blk = blockIdx.x, t = threadIdx.x;
    for (int i = t; i < nbuck; i += 256) h[i] = 0;
    __syncthreads();
    int lo = blk * chunk, hi = min(E, lo + chunk);
    for (int e = lo + t; e < hi; e += 256) atomicAdd(&h[row[e] >> BSHIFT], 1);
    __syncthreads();
    for (int b = t; b < nbuck; b += 256) cnt[b * NBLK_P + blk] = h[b];
}

// ---------------- scan (3-step, exclusive) ----------------
__global__ void scan_block_kernel(const int* __restrict__ in, int* __restrict__ outp,
                                  int* __restrict__ bsum, int M) {
    __shared__ int s[SCAN_B];
    int t = threadIdx.x;
    int g = blockIdx.x * SCAN_B + t;
    int v = (g < M) ? in[g] : 0;
    s[t] = v;
    __syncthreads();
#pragma unroll
    for (int off = 1; off < SCAN_B; off <<= 1) {
        int u = (t >= off) ? s[t - off] : 0;
        __syncthreads();
        s[t] += u;
        __syncthreads();
    }
    if (g < M) outp[g] = s[t] - v;
    if (t == SCAN_B - 1) bsum[blockIdx.x] = s[t];
}

__global__ void scan_bsum_kernel(int* __restrict__ bsum, int NB) {
    __shared__ int s[1024];
    int t = threadIdx.x;
    int v = (t < NB) ? bsum[t] : 0;
    s[t] = v;
    __syncthreads();
#pragma unroll
    for (int off = 1; off < 1024; off <<= 1) {
        int u = (t >= off) ? s[t - off] : 0;
        __syncthreads();
        s[t] += u;
        __syncthreads();
    }
    if (t < NB) bsum[t] = s[t] - v;
}

__global__ void scan_add_kernel(int* __restrict__ outp, const int* __restrict__ bsum, int M) {
    int g = blockIdx.x * blockDim.x + threadIdx.x;
    if (g < M) outp[g] += bsum[g >> 8];
}

// ---------------- P2: partition edges into bucket-ordered packed records ----
__global__ __launch_bounds__(256) void p2_scatter(const int* __restrict__ row,
                                                  const int* __restrict__ col,
                                                  const int* __restrict__ off,
                                                  uint32_t* __restrict__ part,
                                                  int E, int chunk, int nbuck) {
    __shared__ int cur[256];
    const int blk = blockIdx.x, t = threadIdx.x;
    for (int b = t; b < nbuck; b += 256) cur[b] = off[b * NBLK_P + blk];
    __syncthreads();
    int lo = blk * chunk, hi = min(E, lo + chunk);
    for (int e = lo + t; e < hi; e += 256) {
        int r = row[e], c = col[e];
        int pos = atomicAdd(&cur[r >> BSHIFT], 1);
        part[pos] = ((uint32_t)(r & (NPB - 1)) << 17) | (uint32_t)c;
    }
}

// ---------------- P3: per-bucket CSR build (one block per bucket) ----------------
__global__ __launch_bounds__(256) void p3_build(const uint32_t* __restrict__ part,
                                                const int* __restrict__ off,
                                                int* __restrict__ rowptr,
                                                float* __restrict__ dis,
                                                int* __restrict__ csr,
                                                int N, int E, int nbuck) {
    __shared__ int hist[NPB];
    __shared__ int lstart[NPB];
    __shared__ int s[256];
    const int b = blockIdx.x, t = threadIdx.x;
    const int base_node = b << BSHIFT;
    const int csr_base  = off[b * NBLK_P];
    const int end_b     = (b == nbuck - 1) ? E : off[(b + 1) * NBLK_P];

    for (int i = t; i < NPB; i += 256) hist[i] = 0;
    __syncthreads();
    for (int e = csr_base + t; e < end_b; e += 256)
        atomicAdd(&hist[part[e] >> 17], 1);
    __syncthreads();

    int a0 = hist[2 * t], a1 = hist[2 * t + 1];
    s[t] = a0 + a1;
    __syncthreads();
    int v = s[t];
#pragma unroll
    for (int o = 1; o < 256; o <<= 1) {
        int u = (t >= o) ? s[t - o] : 0;
        __syncthreads();
        s[t] += u;
        __syncthreads();
    }
    int ex = s[t] - v;
    lstart[2 * t]     = ex;
    lstart[2 * t + 1] = ex + a0;
    __syncthreads();

    for (int i = t; i < NPB; i += 256) {
        int node = base_node + i;
        if (node < N) {
            rowptr[node] = csr_base + lstart[i];
            dis[node]    = rsqrtf((float)hist[i]);
        }
    }
    __syncthreads();
    for (int i = t; i < NPB; i += 256) hist[i] = lstart[i];
    __syncthreads();
    for (int e = csr_base + t; e < end_b; e += 256) {
        uint32_t p = part[e];
        int pos = csr_base + atomicAdd(&hist[p >> 17], 1);
        csr[pos] = (int)(p & 0x1FFFFu);
    }
    if (b == 0 && t == 0) rowptr[N] = E;
}

// ---------------- wide gather: 4 edges per VMEM instr -----------------------
// lane group g = lane>>4 owns edge slot; li = lane&15 owns 16B channel quad.
// sup row = 16 uint4 (channels pair-packed (ch, ch+64)).
__global__ __launch_bounds__(256) void gather_kernel(const int* __restrict__ csr,
                                                     const int* __restrict__ rowptr,
                                                     const float* __restrict__ dis,
                                                     const uint4* __restrict__ sup,
                                                     const float* __restrict__ bias,
                                                     float* __restrict__ out, int N) {
    int wid  = (blockIdx.x * blockDim.x + threadIdx.x) >> 6;
    int lane = threadIdx.x & 63;
    if (wid >= N) return;
    const int grp = lane >> 4;
    const int li  = lane & 15;
    int begin = rowptr[wid];
    int end   = rowptr[wid + 1];
    float dr  = dis[wid];

    float4 aL = make_float4(0.f, 0.f, 0.f, 0.f);   // channels 4li..4li+3
    float4 aH = make_float4(0.f, 0.f, 0.f, 0.f);   // channels 64+4li..64+4li+3

    for (int j = begin; j < end; j += 8) {
        int e0 = j + grp, e1 = j + 4 + grp;
        int c0 = csr[min(e0, end - 1)];
        int c1 = csr[min(e1, end - 1)];
        float n0 = (e0 < end) ? dr * dis[c0] : 0.f;
        float n1 = (e1 < end) ? dr * dis[c1] : 0.f;
        uint4 u0 = sup[(size_t)c0 * 16 + li];
        uint4 u1 = sup[(size_t)c1 * 16 + li];
        aL.x += n0 * bf_lo(u0.x) + n1 * bf_lo(u1.x);
        aL.y += n0 * bf_lo(u0.y) + n1 * bf_lo(u1.y);
        aL.z += n0 * bf_lo(u0.z) + n1 * bf_lo(u1.z);
        aL.w += n0 * bf_lo(u0.w) + n1 * bf_lo(u1.w);
        aH.x += n0 * bf_hi(u0.x) + n1 * bf_hi(u1.x);
        aH.y += n0 * bf_hi(u0.y) + n1 * bf_hi(u1.y);
        aH.z += n0 * bf_hi(u0.z) + n1 * bf_hi(u1.z);
        aH.w += n0 * bf_hi(u0.w) + n1 * bf_hi(u1.w);
    }

    // fold the 4 edge-slot partials (lanes li, li+16, li+32, li+48)
#pragma unroll
    for (int off = 16; off < 64; off <<= 1) {
        aL.x += __shfl_xor(aL.x, off);
        aL.y += __shfl_xor(aL.y, off);
        aL.z += __shfl_xor(aL.z, off);
        aL.w += __shfl_xor(aL.w, off);
        aH.x += __shfl_xor(aH.x, off);
        aH.y += __shfl_xor(aH.y, off);
        aH.z += __shfl_xor(aH.z, off);
        aH.w += __shfl_xor(aH.w, off);
    }

    if (grp == 0) {
        float4 bL = *(const float4*)(bias + li * 4);
        float4 bH = *(const float4*)(bias + 64 + li * 4);
        aL.x += bL.x; aL.y += bL.y; aL.z += bL.z; aL.w += bL.w;
        aH.x += bH.x; aH.y += bH.y; aH.z += bH.z; aH.w += bH.w;
        *(float4*)(out + (size_t)wid * 128 + li * 4)      = aL;
        *(float4*)(out + (size_t)wid * 128 + 64 + li * 4) = aH;
    }
}

// ---------------- fallback fp32 GEMM (epilogue matches (ch,ch+64) pairs) -----
#define GB_M 64
#define GB_KC 32
__global__ __launch_bounds__(256) void gemm_kernel(const float* __restrict__ X,
                                                   const float* __restrict__ W,
                                                   uint32_t* __restrict__ S, int N) {
    __shared__ float sXT[GB_KC][72];
    __shared__ float sW[GB_KC][128];
    const int t  = threadIdx.x;
    const int tx = t & 15;
    const int ty = t >> 4;
    const int bm = blockIdx.x * GB_M;

    float acc[4][8];
#pragma unroll
    for (int i = 0; i < 4; ++i)
#pragma unroll
        for (int j = 0; j < 8; ++j) acc[i][j] = 0.f;

    const int sr = t >> 2;
    const int sc = (t & 3) << 2;

    for (int k0 = 0; k0 < 128; k0 += GB_KC) {
#pragma unroll
        for (int h = 0; h < 2; ++h) {
            int kk = sc + h * 16;
            int gr = bm + sr;
            float4 v = make_float4(0.f, 0.f, 0.f, 0.f);
            if (gr < N) v = *(const float4*)(X + (size_t)gr * 128 + k0 + kk);
            sXT[kk + 0][sr] = v.x;
            sXT[kk + 1][sr] = v.y;
            sXT[kk + 2][sr] = v.z;
            sXT[kk + 3][sr] = v.w;
        }
#pragma unroll
        for (int h = 0; h < 4; ++h) {
            int idx = t + h * 256;
            int wk  = idx >> 5;
            int wo  = (idx & 31) << 2;
            *(float4*)&sW[wk][wo] = *(const float4*)(W + (size_t)(k0 + wk) * 128 + wo);
        }
        __syncthreads();
#pragma unroll
        for (int k = 0; k < GB_KC; ++k) {
            float4 a  = *(const float4*)&sXT[k][ty * 4];
            float4 b0 = *(const float4*)&sW[k][tx * 4];
            float4 b1 = *(const float4*)&sW[k][64 + tx * 4];
            float av[4] = {a.x, a.y, a.z, a.w};
            float bv[8] = {b0.x, b0.y, b0.z, b0.w, b1.x, b1.y, b1.z, b1.w};
#pragma unroll
            for (int i = 0; i < 4; ++i)
#pragma unroll
                for (int j = 0; j < 8; ++j) acc[i][j] += av[i] * bv[j];
        }
        __syncthreads();
    }
#pragma unroll
    for (int i = 0; i < 4; ++i) {
        int gr = bm + ty * 4 + i;
        if (gr < N) {
            uint4 q;
            q.x = f2bf_rne(acc[i][0]) | (f2bf_rne(acc[i][4]) << 16);
            q.y = f2bf_rne(acc[i][1]) | (f2bf_rne(acc[i][5]) << 16);
            q.z = f2bf_rne(acc[i][2]) | (f2bf_rne(acc[i][6]) << 16);
            q.w = f2bf_rne(acc[i][3]) | (f2bf_rne(acc[i][7]) << 16);
            *(uint4*)(S + (size_t)gr * 64 + tx * 4) = q;
        }
    }
}

// ---------------- fallback CSR-build kernels ----------------
__global__ void deg_i_kernel(const int* __restrict__ row, int* __restrict__ degi, int E) {
    int g = blockIdx.x * blockDim.x + threadIdx.x;
    if (g < E) atomicAdd(&degi[row[g]], 1);
}
__global__ void rsqrt_i_kernel(const int* __restrict__ degi, float* __restrict__ dis, int N) {
    int g = blockIdx.x * blockDim.x + threadIdx.x;
    if (g < N) dis[g] = rsqrtf((float)degi[g]);
}
__global__ void fill_kernel(const int* __restrict__ row, const int* __restrict__ col,
                            int* __restrict__ start, int* __restrict__ csr, int E) {
    int e = blockIdx.x * blockDim.x + threadIdx.x;
    if (e < E) {
        int pos = atomicAdd(&start[row[e]], 1);
        csr[pos] = col[e];
    }
}
__global__ void rowptr_from_start_kernel(const int* __restrict__ startv,
                                         int* __restrict__ rowptr, int N, int E) {
    int g = blockIdx.x * blockDim.x + threadIdx.x;
    if (g < N) rowptr[g] = startv[g];
    if (g == 0) rowptr[N] = E;
}

extern "C" void kernel_launch(void* const* d_in, const int* in_sizes, int n_in,
                              void* d_out, int out_size, void* d_ws, size_t ws_size,
                              hipStream_t stream) {
    const float* x    = (const float*)d_in[0];
    const int*   ei   = (const int*)d_in[1];
    const float* W    = (const float*)d_in[2];
    const float* bias = (const float*)d_in[3];
    float*       out  = (float*)d_out;

    const int N = in_sizes[0] / 128;
    const int E = in_sizes[1] / 2;
    const int* row = ei;
    const int* col = ei + E;

    const int nbuck = (N + NPB - 1) >> BSHIFT;
    const int M     = nbuck * NBLK_P;
    const int chunk = (E + NBLK_P - 1) / NBLK_P;
    const int NBm   = (M + SCAN_B - 1) / SCAN_B;

    auto al = [](size_t v) { return (v + 511) & ~(size_t)511; };
    size_t o_cnt    = 0;
    size_t o_off    = al(o_cnt + (size_t)M * 4);
    size_t o_bsum   = al(o_off + (size_t)M * 4);
    size_t o_rowptr = al(o_bsum + 4096 * 4);
    size_t o_dis    = al(o_rowptr + ((size_t)N + 1) * 4);
    size_t o_csr    = al(o_dis + (size_t)N * 4);
    size_t o_part   = al(o_csr + (size_t)E * 4);
    size_t o_wt     = al(o_part + (size_t)E * 4);
    size_t o_sup    = al(o_wt + 128 * 128 * 2);
    size_t need     = o_sup + (size_t)N * 256;   // bf16 support

    char* ws = (char*)d_ws;

    if (ws_size >= need && nbuck <= 256 && NBm <= 1024 && N <= (1 << 17)) {
        int*      cnt    = (int*)(ws + o_cnt);
        int*      off    = (int*)(ws + o_off);
        int*      bsum   = (int*)(ws + o_bsum);
        int*      rowptr = (int*)(ws + o_rowptr);
        float*    dis    = (float*)(ws + o_dis);
        int*      csr    = (int*)(ws + o_csr);
        uint32_t* part   = (uint32_t*)(ws + o_part);
        ushort*   wt     = (ushort*)(ws + o_wt);
        uint4*    sup    = (uint4*)(ws + o_sup);

        wconv_kernel<<<64, 256, 0, stream>>>(W, wt);
        mfma_gemm<<<(N + 127) / 128, 256, 0, stream>>>(x, wt, (uint32_t*)sup, N);

        p1_count<<<NBLK_P, 256, 0, stream>>>(row, cnt, E, chunk, nbuck);
        scan_block_kernel<<<NBm, SCAN_B, 0, stream>>>(cnt, off, bsum, M);
        scan_bsum_kernel<<<1, 1024, 0, stream>>>(bsum, NBm);
        scan_add_kernel<<<NBm, SCAN_B, 0, stream>>>(off, bsum, M);
        p2_scatter<<<NBLK_P, 256, 0, stream>>>(row, col, off, part, E, chunk, nbuck);
        p3_build<<<nbuck, 256, 0, stream>>>(part, off, rowptr, dis, csr, N, E, nbuck);

        long long gthreads = (long long)N * 64;
        gather_kernel<<<(int)((gthreads + 255) / 256), 256, 0, stream>>>(
            csr, rowptr, dis, sup, bias, out, N);
    } else {
        // fallback: global-atomic CSR build + fp32 LDS GEMM + same gather
        size_t f_degi   = 0;
        size_t f_dis    = al(f_degi + (size_t)N * 4);
        size_t f_start  = al(f_dis + (size_t)N * 4);
        size_t f_rowptr = al(f_start + (size_t)N * 4);
        size_t f_bsum   = al(f_rowptr + ((size_t)N + 1) * 4);
        size_t f_csr    = al(f_bsum + 4096 * 4);
        size_t f_sup    = al(f_csr + (size_t)E * 4);

        int*      degi   = (int*)(ws + f_degi);
        float*    dis    = (float*)(ws + f_dis);
        int*      startv = (int*)(ws + f_start);
        int*      rowptr = (int*)(ws + f_rowptr);
        int*      bsum   = (int*)(ws + f_bsum);
        int*      csr    = (int*)(ws + f_csr);
        uint4*    sup    = (uint4*)(ws + f_sup);
        const int NBn = (N + SCAN_B - 1) / SCAN_B;

        hipMemsetAsync(degi, 0, (size_t)N * 4, stream);
        gemm_kernel<<<(N + GB_M - 1) / GB_M, 256, 0, stream>>>(x, W, (uint32_t*)sup, N);
        deg_i_kernel<<<(E + 255) / 256, 256, 0, stream>>>(row, degi, E);
        scan_block_kernel<<<NBn, SCAN_B, 0, stream>>>(degi, startv, bsum, N);
        scan_bsum_kernel<<<1, 1024, 0, stream>>>(bsum, NBn);
        scan_add_kernel<<<NBn, SCAN_B, 0, stream>>>(startv, bsum, N);
        rowptr_from_start_kernel<<<NBn, SCAN_B, 0, stream>>>(startv, rowptr, N, E);
        rsqrt_i_kernel<<<NBn, SCAN_B, 0, stream>>>(degi, dis, N);
        fill_kernel<<<(E + 255) / 256, 256, 0, stream>>>(row, col, startv, csr, E);
        long long gthreads = (long long)N * 64;
        gather_kernel<<<(int)((gthreads + 255) / 256), 256, 0, stream>>>(
            csr, rowptr, dis, sup, bias, out, N);
    }
}

// Round 7
// 155.841 us; speedup vs baseline: 9.8127x; 1.0504x over previous
//
#include <hip/hip_runtime.h>
#include <hip/hip_bf16.h>

// GCNConv: out = scatter_add_row( norm[e] * (x@W)[col[e]] ) + bias
// Round 7: gather is at the 6.3 TB/s delivery roofline (invariant across 3
// structures). Speed up the build: 512 partition blocks, 256-node buckets,
// scan_add folded into p2/p3.

#define SCAN_B 256
#define NBLK_P 512      // partition blocks
#define BSHIFT 8        // 256 nodes per bucket
#define NPB    256      // nodes per bucket

typedef __attribute__((ext_vector_type(8))) short bf16x8;
typedef __attribute__((ext_vector_type(4))) float f32x4;

__device__ __forceinline__ uint32_t f2bf_rne(float f) {
    uint32_t u = __float_as_uint(f);
    return (u + 0x7fffu + ((u >> 16) & 1u)) >> 16;
}
__device__ __forceinline__ float bf_lo(uint32_t u) { return __uint_as_float(u << 16); }
__device__ __forceinline__ float bf_hi(uint32_t u) { return __uint_as_float(u & 0xffff0000u); }

__device__ __forceinline__ bf16x8 pack8(float4 lo, float4 hi) {
    union { bf16x8 v; ushort u[8]; } r;
    r.u[0] = (ushort)f2bf_rne(lo.x);
    r.u[1] = (ushort)f2bf_rne(lo.y);
    r.u[2] = (ushort)f2bf_rne(lo.z);
    r.u[3] = (ushort)f2bf_rne(lo.w);
    r.u[4] = (ushort)f2bf_rne(hi.x);
    r.u[5] = (ushort)f2bf_rne(hi.y);
    r.u[6] = (ushort)f2bf_rne(hi.z);
    r.u[7] = (ushort)f2bf_rne(hi.w);
    return r.v;
}

// ---------------- W -> Wt bf16 transposed [n][k] ----------------
__global__ void wconv_kernel(const float* __restrict__ W, ushort* __restrict__ Wt) {
    int t = blockIdx.x * blockDim.x + threadIdx.x;   // 0..16383
    int n = t >> 7, k = t & 127;
    Wt[n * 128 + k] = (ushort)f2bf_rne(W[k * 128 + n]);
}

// ---------------- MFMA GEMM: S[N,128](bf16 pairs ch,ch+64) = X @ W ----------
__global__ __launch_bounds__(256) void mfma_gemm(const float* __restrict__ X,
                                                 const ushort* __restrict__ Wt,
                                                 uint32_t* __restrict__ S, int N) {
    const int wave = threadIdx.x >> 6;
    const int lane = threadIdx.x & 63;
    const int c16  = lane & 15;
    const int kg   = lane >> 4;
    const int row0 = blockIdx.x * 128 + wave * 32;

    int rA0 = row0 + c16;
    int rA1 = row0 + 16 + c16;
    if (rA0 >= N) rA0 = N - 1;
    if (rA1 >= N) rA1 = N - 1;

    f32x4 acc[2][8];
#pragma unroll
    for (int m = 0; m < 2; ++m)
#pragma unroll
        for (int cb = 0; cb < 8; ++cb) acc[m][cb] = (f32x4){0.f, 0.f, 0.f, 0.f};

    const float*  xa0 = X + (size_t)rA0 * 128 + kg * 8;
    const float*  xa1 = X + (size_t)rA1 * 128 + kg * 8;
    const ushort* wb  = Wt + kg * 8 + c16 * 128;

#pragma unroll
    for (int kk = 0; kk < 4; ++kk) {
        float4 a0lo = *(const float4*)(xa0 + kk * 32);
        float4 a0hi = *(const float4*)(xa0 + kk * 32 + 4);
        float4 a1lo = *(const float4*)(xa1 + kk * 32);
        float4 a1hi = *(const float4*)(xa1 + kk * 32 + 4);
        bf16x8 A0 = pack8(a0lo, a0hi);
        bf16x8 A1 = pack8(a1lo, a1hi);
#pragma unroll
        for (int cb = 0; cb < 8; ++cb) {
            bf16x8 B = *(const bf16x8*)(wb + (size_t)cb * 16 * 128 + kk * 32);
            acc[0][cb] = __builtin_amdgcn_mfma_f32_16x16x32_bf16(A0, B, acc[0][cb], 0, 0, 0);
            acc[1][cb] = __builtin_amdgcn_mfma_f32_16x16x32_bf16(A1, B, acc[1][cb], 0, 0, 0);
        }
    }
#pragma unroll
    for (int m = 0; m < 2; ++m) {
#pragma unroll
        for (int i = 0; i < 4; ++i) {
            int gr = row0 + m * 16 + kg * 4 + i;
            if (gr < N) {
#pragma unroll
                for (int cb = 0; cb < 4; ++cb) {
                    uint32_t p = f2bf_rne(acc[m][cb][i]) |
                                 (f2bf_rne(acc[m][cb + 4][i]) << 16);
                    S[(size_t)gr * 64 + cb * 16 + c16] = p;
                }
            }
        }
    }
}

// ---------------- P1: per-block bucket histogram ----------------
__global__ __launch_bounds__(256) void p1_count(const int* __restrict__ row,
                                                int* __restrict__ cnt,
                                                int E, int chunk, int nbuck) {
    __shared__ int h[512];
    const int blk = blockIdx.x, t = threadIdx.x;
    for (int i = t; i < nbuck; i += 256) h[i] = 0;
    __syncthreads();
    int lo = blk * chunk, hi = min(E, lo + chunk);
    for (int e = lo + t; e < hi; e += 256) atomicAdd(&h[row[e] >> BSHIFT], 1);
    __syncthreads();
    for (int b = t; b < nbuck; b += 256) cnt[b * NBLK_P + blk] = h[b];
}

// ---------------- scan (2 kernels; final add folded into consumers) ---------
__global__ void scan_block_kernel(const int* __restrict__ in, int* __restrict__ outp,
                                  int* __restrict__ bsum, int M) {
    __shared__ int s[SCAN_B];
    int t = threadIdx.x;
    int g = blockIdx.x * SCAN_B + t;
    int v = (g < M) ? in[g] : 0;
    s[t] = v;
    __syncthreads();
#pragma unroll
    for (int off = 1; off < SCAN_B; off <<= 1) {
        int u = (t >= off) ? s[t - off] : 0;
        __syncthreads();
        s[t] += u;
        __syncthreads();
    }
    if (g < M) outp[g] = s[t] - v;
    if (t == SCAN_B - 1) bsum[blockIdx.x] = s[t];
}

__global__ void scan_bsum_kernel(int* __restrict__ bsum, int NB) {
    __shared__ int s[1024];
    int t = threadIdx.x;
    int v = (t < NB) ? bsum[t] : 0;
    s[t] = v;
    __syncthreads();
#pragma unroll
    for (int off = 1; off < 1024; off <<= 1) {
        int u = (t >= off) ? s[t - off] : 0;
        __syncthreads();
        s[t] += u;
        __syncthreads();
    }
    if (t < NB) bsum[t] = s[t] - v;
}

// ---------------- P2: partition edges into bucket-ordered packed records ----
// off_final[i] = outp[i] + bsum[i>>8] computed inline.
__global__ __launch_bounds__(256) void p2_scatter(const int* __restrict__ row,
                                                  const int* __restrict__ col,
                                                  const int* __restrict__ outp,
                                                  const int* __restrict__ bsum,
                                                  uint32_t* __restrict__ part,
                                                  int E, int chunk, int nbuck) {
    __shared__ int cur[512];
    const int blk = blockIdx.x, t = threadIdx.x;
    for (int b = t; b < nbuck; b += 256) {
        int idx = b * NBLK_P + blk;
        cur[b] = outp[idx] + bsum[idx >> 8];
    }
    __syncthreads();
    int lo = blk * chunk, hi = min(E, lo + chunk);
    for (int e = lo + t; e < hi; e += 256) {
        int r = row[e], c = col[e];
        int pos = atomicAdd(&cur[r >> BSHIFT], 1);
        part[pos] = ((uint32_t)(r & (NPB - 1)) << 17) | (uint32_t)c;
    }
}

// ---------------- P3: per-bucket CSR build (one block per bucket) ----------------
__global__ __launch_bounds__(256) void p3_build(const uint32_t* __restrict__ part,
                                                const int* __restrict__ outp,
                                                const int* __restrict__ bsum,
                                                int* __restrict__ rowptr,
                                                float* __restrict__ dis,
                                                int* __restrict__ csr,
                                                int N, int E, int nbuck) {
    __shared__ int hist[NPB];
    __shared__ int lstart[NPB];
    __shared__ int s[NPB];
    const int b = blockIdx.x, t = threadIdx.x;   // blockDim = 256 = NPB
    const int base_node = b << BSHIFT;
    int ib = b * NBLK_P;
    const int csr_base = outp[ib] + bsum[ib >> 8];
    int end_b;
    if (b == nbuck - 1) end_b = E;
    else {
        int ie = (b + 1) * NBLK_P;
        end_b = outp[ie] + bsum[ie >> 8];
    }

    hist[t] = 0;
    __syncthreads();
    for (int e = csr_base + t; e < end_b; e += 256)
        atomicAdd(&hist[part[e] >> 17], 1);
    __syncthreads();

    // exclusive scan of hist[0..255]
    int v = hist[t];
    s[t] = v;
    __syncthreads();
#pragma unroll
    for (int o = 1; o < NPB; o <<= 1) {
        int u = (t >= o) ? s[t - o] : 0;
        __syncthreads();
        s[t] += u;
        __syncthreads();
    }
    lstart[t] = s[t] - v;
    __syncthreads();

    int node = base_node + t;
    if (node < N) {
        rowptr[node] = csr_base + lstart[t];
        dis[node]    = rsqrtf((float)hist[t]);
    }
    __syncthreads();
    hist[t] = lstart[t];
    __syncthreads();
    for (int e = csr_base + t; e < end_b; e += 256) {
        uint32_t p = part[e];
        int pos = csr_base + atomicAdd(&hist[p >> 17], 1);
        csr[pos] = (int)(p & 0x1FFFFu);
    }
    if (b == 0 && t == 0) rowptr[N] = E;
}

// ---------------- wide gather: 4 edges per VMEM instr (at roofline) ---------
__global__ __launch_bounds__(256) void gather_kernel(const int* __restrict__ csr,
                                                     const int* __restrict__ rowptr,
                                                     const float* __restrict__ dis,
                                                     const uint4* __restrict__ sup,
                                                     const float* __restrict__ bias,
                                                     float* __restrict__ out, int N) {
    int wid  = (blockIdx.x * blockDim.x + threadIdx.x) >> 6;
    int lane = threadIdx.x & 63;
    if (wid >= N) return;
    const int grp = lane >> 4;
    const int li  = lane & 15;
    int begin = rowptr[wid];
    int end   = rowptr[wid + 1];
    int endm1 = end - 1;
    float dr  = dis[wid];

    float4 aL = make_float4(0.f, 0.f, 0.f, 0.f);
    float4 aH = make_float4(0.f, 0.f, 0.f, 0.f);

    for (int j = begin; j < end; j += 8) {
        int e0 = j + grp, e1 = j + 4 + grp;
        int c0 = csr[min(e0, endm1)];
        int c1 = csr[min(e1, endm1)];
        float n0 = (e0 < end) ? dr * dis[c0] : 0.f;
        float n1 = (e1 < end) ? dr * dis[c1] : 0.f;
        uint4 u0 = sup[(size_t)c0 * 16 + li];
        uint4 u1 = sup[(size_t)c1 * 16 + li];
        aL.x += n0 * bf_lo(u0.x) + n1 * bf_lo(u1.x);
        aL.y += n0 * bf_lo(u0.y) + n1 * bf_lo(u1.y);
        aL.z += n0 * bf_lo(u0.z) + n1 * bf_lo(u1.z);
        aL.w += n0 * bf_lo(u0.w) + n1 * bf_lo(u1.w);
        aH.x += n0 * bf_hi(u0.x) + n1 * bf_hi(u1.x);
        aH.y += n0 * bf_hi(u0.y) + n1 * bf_hi(u1.y);
        aH.z += n0 * bf_hi(u0.z) + n1 * bf_hi(u1.z);
        aH.w += n0 * bf_hi(u0.w) + n1 * bf_hi(u1.w);
    }

#pragma unroll
    for (int off = 16; off < 64; off <<= 1) {
        aL.x += __shfl_xor(aL.x, off);
        aL.y += __shfl_xor(aL.y, off);
        aL.z += __shfl_xor(aL.z, off);
        aL.w += __shfl_xor(aL.w, off);
        aH.x += __shfl_xor(aH.x, off);
        aH.y += __shfl_xor(aH.y, off);
        aH.z += __shfl_xor(aH.z, off);
        aH.w += __shfl_xor(aH.w, off);
    }

    if (grp == 0) {
        float4 bL = *(const float4*)(bias + li * 4);
        float4 bH = *(const float4*)(bias + 64 + li * 4);
        aL.x += bL.x; aL.y += bL.y; aL.z += bL.z; aL.w += bL.w;
        aH.x += bH.x; aH.y += bH.y; aH.z += bH.z; aH.w += bH.w;
        *(float4*)(out + (size_t)wid * 128 + li * 4)      = aL;
        *(float4*)(out + (size_t)wid * 128 + 64 + li * 4) = aH;
    }
}

// ---------------- fallback path (global-atomic CSR build) ----------------
__global__ void scan_add_kernel(int* __restrict__ outp, const int* __restrict__ bsum, int M) {
    int g = blockIdx.x * blockDim.x + threadIdx.x;
    if (g < M) outp[g] += bsum[g >> 8];
}
#define GB_M 64
#define GB_KC 32
__global__ __launch_bounds__(256) void gemm_kernel(const float* __restrict__ X,
                                                   const float* __restrict__ W,
                                                   uint32_t* __restrict__ S, int N) {
    __shared__ float sXT[GB_KC][72];
    __shared__ float sW[GB_KC][128];
    const int t  = threadIdx.x;
    const int tx = t & 15;
    const int ty = t >> 4;
    const int bm = blockIdx.x * GB_M;

    float acc[4][8];
#pragma unroll
    for (int i = 0; i < 4; ++i)
#pragma unroll
        for (int j = 0; j < 8; ++j) acc[i][j] = 0.f;

    const int sr = t >> 2;
    const int sc = (t & 3) << 2;

    for (int k0 = 0; k0 < 128; k0 += GB_KC) {
#pragma unroll
        for (int h = 0; h < 2; ++h) {
            int kk = sc + h * 16;
            int gr = bm + sr;
            float4 v = make_float4(0.f, 0.f, 0.f, 0.f);
            if (gr < N) v = *(const float4*)(X + (size_t)gr * 128 + k0 + kk);
            sXT[kk + 0][sr] = v.x;
            sXT[kk + 1][sr] = v.y;
            sXT[kk + 2][sr] = v.z;
            sXT[kk + 3][sr] = v.w;
        }
#pragma unroll
        for (int h = 0; h < 4; ++h) {
            int idx = t + h * 256;
            int wk  = idx >> 5;
            int wo  = (idx & 31) << 2;
            *(float4*)&sW[wk][wo] = *(const float4*)(W + (size_t)(k0 + wk) * 128 + wo);
        }
        __syncthreads();
#pragma unroll
        for (int k = 0; k < GB_KC; ++k) {
            float4 a  = *(const float4*)&sXT[k][ty * 4];
            float4 b0 = *(const float4*)&sW[k][tx * 4];
            float4 b1 = *(const float4*)&sW[k][64 + tx * 4];
            float av[4] = {a.x, a.y, a.z, a.w};
            float bv[8] = {b0.x, b0.y, b0.z, b0.w, b1.x, b1.y, b1.z, b1.w};
#pragma unroll
            for (int i = 0; i < 4; ++i)
#pragma unroll
                for (int j = 0; j < 8; ++j) acc[i][j] += av[i] * bv[j];
        }
        __syncthreads();
    }
#pragma unroll
    for (int i = 0; i < 4; ++i) {
        int gr = bm + ty * 4 + i;
        if (gr < N) {
            uint4 q;
            q.x = f2bf_rne(acc[i][0]) | (f2bf_rne(acc[i][4]) << 16);
            q.y = f2bf_rne(acc[i][1]) | (f2bf_rne(acc[i][5]) << 16);
            q.z = f2bf_rne(acc[i][2]) | (f2bf_rne(acc[i][6]) << 16);
            q.w = f2bf_rne(acc[i][3]) | (f2bf_rne(acc[i][7]) << 16);
            *(uint4*)(S + (size_t)gr * 64 + tx * 4) = q;
        }
    }
}
__global__ void deg_i_kernel(const int* __restrict__ row, int* __restrict__ degi, int E) {
    int g = blockIdx.x * blockDim.x + threadIdx.x;
    if (g < E) atomicAdd(&degi[row[g]], 1);
}
__global__ void rsqrt_i_kernel(const int* __restrict__ degi, float* __restrict__ dis, int N) {
    int g = blockIdx.x * blockDim.x + threadIdx.x;
    if (g < N) dis[g] = rsqrtf((float)degi[g]);
}
__global__ void fill_kernel(const int* __restrict__ row, const int* __restrict__ col,
                            int* __restrict__ start, int* __restrict__ csr, int E) {
    int e = blockIdx.x * blockDim.x + threadIdx.x;
    if (e < E) {
        int pos = atomicAdd(&start[row[e]], 1);
        csr[pos] = col[e];
    }
}
__global__ void rowptr_from_start_kernel(const int* __restrict__ startv,
                                         int* __restrict__ rowptr, int N, int E) {
    int g = blockIdx.x * blockDim.x + threadIdx.x;
    if (g < N) rowptr[g] = startv[g];
    if (g == 0) rowptr[N] = E;
}

extern "C" void kernel_launch(void* const* d_in, const int* in_sizes, int n_in,
                              void* d_out, int out_size, void* d_ws, size_t ws_size,
                              hipStream_t stream) {
    const float* x    = (const float*)d_in[0];
    const int*   ei   = (const int*)d_in[1];
    const float* W    = (const float*)d_in[2];
    const float* bias = (const float*)d_in[3];
    float*       out  = (float*)d_out;

    const int N = in_sizes[0] / 128;
    const int E = in_sizes[1] / 2;
    const int* row = ei;
    const int* col = ei + E;

    const int nbuck = (N + NPB - 1) >> BSHIFT;
    const int M     = nbuck * NBLK_P;
    const int chunk = (E + NBLK_P - 1) / NBLK_P;
    const int NBm   = (M + SCAN_B - 1) / SCAN_B;

    auto al = [](size_t v) { return (v + 511) & ~(size_t)511; };
    size_t o_cnt    = 0;
    size_t o_off    = al(o_cnt + (size_t)M * 4);
    size_t o_bsum   = al(o_off + (size_t)M * 4);
    size_t o_rowptr = al(o_bsum + 4096 * 4);
    size_t o_dis    = al(o_rowptr + ((size_t)N + 1) * 4);
    size_t o_csr    = al(o_dis + (size_t)N * 4);
    size_t o_part   = al(o_csr + (size_t)E * 4);
    size_t o_wt     = al(o_part + (size_t)E * 4);
    size_t o_sup    = al(o_wt + 128 * 128 * 2);
    size_t need     = o_sup + (size_t)N * 256;   // bf16 support

    char* ws = (char*)d_ws;

    if (ws_size >= need && nbuck <= 512 && NBm <= 1024 && N <= (1 << 17)) {
        int*      cnt    = (int*)(ws + o_cnt);
        int*      off    = (int*)(ws + o_off);
        int*      bsum   = (int*)(ws + o_bsum);
        int*      rowptr = (int*)(ws + o_rowptr);
        float*    dis    = (float*)(ws + o_dis);
        int*      csr    = (int*)(ws + o_csr);
        uint32_t* part   = (uint32_t*)(ws + o_part);
        ushort*   wt     = (ushort*)(ws + o_wt);
        uint4*    sup    = (uint4*)(ws + o_sup);

        wconv_kernel<<<64, 256, 0, stream>>>(W, wt);
        mfma_gemm<<<(N + 127) / 128, 256, 0, stream>>>(x, wt, (uint32_t*)sup, N);

        p1_count<<<NBLK_P, 256, 0, stream>>>(row, cnt, E, chunk, nbuck);
        scan_block_kernel<<<NBm, SCAN_B, 0, stream>>>(cnt, off, bsum, M);
        scan_bsum_kernel<<<1, 1024, 0, stream>>>(bsum, NBm);
        p2_scatter<<<NBLK_P, 256, 0, stream>>>(row, col, off, bsum, part, E, chunk, nbuck);
        p3_build<<<nbuck, 256, 0, stream>>>(part, off, bsum, rowptr, dis, csr, N, E, nbuck);

        long long gthreads = (long long)N * 64;
        gather_kernel<<<(int)((gthreads + 255) / 256), 256, 0, stream>>>(
            csr, rowptr, dis, sup, bias, out, N);
    } else {
        // fallback: global-atomic CSR build + fp32 LDS GEMM + same gather
        size_t f_degi   = 0;
        size_t f_dis    = al(f_degi + (size_t)N * 4);
        size_t f_start  = al(f_dis + (size_t)N * 4);
        size_t f_rowptr = al(f_start + (size_t)N * 4);
        size_t f_bsum   = al(f_rowptr + ((size_t)N + 1) * 4);
        size_t f_csr    = al(f_bsum + 4096 * 4);
        size_t f_sup    = al(f_csr + (size_t)E * 4);

        int*      degi   = (int*)(ws + f_degi);
        float*    dis    = (float*)(ws + f_dis);
        int*      startv = (int*)(ws + f_start);
        int*      rowptr = (int*)(ws + f_rowptr);
        int*      bsum   = (int*)(ws + f_bsum);
        int*      csr    = (int*)(ws + f_csr);
        uint4*    sup    = (uint4*)(ws + f_sup);
        const int NBn = (N + SCAN_B - 1) / SCAN_B;

        hipMemsetAsync(degi, 0, (size_t)N * 4, stream);
        gemm_kernel<<<(N + GB_M - 1) / GB_M, 256, 0, stream>>>(x, W, (uint32_t*)sup, N);
        deg_i_kernel<<<(E + 255) / 256, 256, 0, stream>>>(row, degi, E);
        scan_block_kernel<<<NBn, SCAN_B, 0, stream>>>(degi, startv, bsum, N);
        scan_bsum_kernel<<<1, 1024, 0, stream>>>(bsum, NBn);
        scan_add_kernel<<<NBn, SCAN_B, 0, stream>>>(startv, bsum, N);
        rowptr_from_start_kernel<<<NBn, SCAN_B, 0, stream>>>(startv, rowptr, N, E);
        rsqrt_i_kernel<<<NBn, SCAN_B, 0, stream>>>(degi, dis, N);
        fill_kernel<<<(E + 255) / 256, 256, 0, stream>>>(row, col, startv, csr, E);
        long long gthreads = (long long)N * 64;
        gather_kernel<<<(int)((gthreads + 255) / 256), 256, 0, stream>>>(
            csr, rowptr, dis, sup, bias, out, N);
    }
}

// Round 8
// 146.261 us; speedup vs baseline: 10.4554x; 1.0655x over previous
//
#include <hip/hip_runtime.h>
#include <hip/hip_bf16.h>

// GCNConv: out = scatter_add_row( norm[e] * (x@W)[col[e]] ) + bias
// Round 8: 4-launch pipeline. Fixed-capacity bucket slots kill the global
// scan; {p1,scan,scan_bsum,p2} collapse into one kernel merged with the
// MFMA GEMM (disjoint block ranges). Gather (at roofline) untouched.

#define NBLK_B 512      // build blocks in merged kernel
#define BSHIFT 7        // 128 nodes per bucket
#define NPB    128

typedef __attribute__((ext_vector_type(8))) short bf16x8;
typedef __attribute__((ext_vector_type(4))) float f32x4;

__device__ __forceinline__ uint32_t f2bf_rne(float f) {
    uint32_t u = __float_as_uint(f);
    return (u + 0x7fffu + ((u >> 16) & 1u)) >> 16;
}
__device__ __forceinline__ float bf_lo(uint32_t u) { return __uint_as_float(u << 16); }
__device__ __forceinline__ float bf_hi(uint32_t u) { return __uint_as_float(u & 0xffff0000u); }

__device__ __forceinline__ bf16x8 pack8(float4 lo, float4 hi) {
    union { bf16x8 v; ushort u[8]; } r;
    r.u[0] = (ushort)f2bf_rne(lo.x);
    r.u[1] = (ushort)f2bf_rne(lo.y);
    r.u[2] = (ushort)f2bf_rne(lo.z);
    r.u[3] = (ushort)f2bf_rne(lo.w);
    r.u[4] = (ushort)f2bf_rne(hi.x);
    r.u[5] = (ushort)f2bf_rne(hi.y);
    r.u[6] = (ushort)f2bf_rne(hi.z);
    r.u[7] = (ushort)f2bf_rne(hi.w);
    return r.v;
}

// ---------------- W -> Wt bf16 transposed; also zero bucket cursors ---------
__global__ void wconv_kernel(const float* __restrict__ W, ushort* __restrict__ Wt,
                             int* __restrict__ gcur, int nbuck) {
    int t = blockIdx.x * blockDim.x + threadIdx.x;   // 0..16383
    int n = t >> 7, k = t & 127;
    Wt[n * 128 + k] = (ushort)f2bf_rne(W[k * 128 + n]);
    if (t < nbuck) gcur[t] = 0;
}

// ---------------- merged: MFMA GEMM blocks + edge-partition blocks ----------
__global__ __launch_bounds__(256) void merged_kernel(
        const float* __restrict__ X, const ushort* __restrict__ Wt,
        uint32_t* __restrict__ S, int N,
        const int* __restrict__ row, const int* __restrict__ col,
        uint32_t* __restrict__ part, int* __restrict__ gcur,
        int E, int chunk, int nbuck, int cap, int GB) {
    __shared__ int h[1024];
    if ((int)blockIdx.x < GB) {
        // ---------- GEMM: S[N,128](bf16 pairs ch,ch+64) = X @ W ----------
        const int wave = threadIdx.x >> 6;
        const int lane = threadIdx.x & 63;
        const int c16  = lane & 15;
        const int kg   = lane >> 4;
        const int row0 = blockIdx.x * 128 + wave * 32;

        int rA0 = row0 + c16;
        int rA1 = row0 + 16 + c16;
        if (rA0 >= N) rA0 = N - 1;
        if (rA1 >= N) rA1 = N - 1;

        f32x4 acc[2][8];
#pragma unroll
        for (int m = 0; m < 2; ++m)
#pragma unroll
            for (int cb = 0; cb < 8; ++cb) acc[m][cb] = (f32x4){0.f, 0.f, 0.f, 0.f};

        const float*  xa0 = X + (size_t)rA0 * 128 + kg * 8;
        const float*  xa1 = X + (size_t)rA1 * 128 + kg * 8;
        const ushort* wb  = Wt + kg * 8 + c16 * 128;

#pragma unroll
        for (int kk = 0; kk < 4; ++kk) {
            float4 a0lo = *(const float4*)(xa0 + kk * 32);
            float4 a0hi = *(const float4*)(xa0 + kk * 32 + 4);
            float4 a1lo = *(const float4*)(xa1 + kk * 32);
            float4 a1hi = *(const float4*)(xa1 + kk * 32 + 4);
            bf16x8 A0 = pack8(a0lo, a0hi);
            bf16x8 A1 = pack8(a1lo, a1hi);
#pragma unroll
            for (int cb = 0; cb < 8; ++cb) {
                bf16x8 B = *(const bf16x8*)(wb + (size_t)cb * 16 * 128 + kk * 32);
                acc[0][cb] = __builtin_amdgcn_mfma_f32_16x16x32_bf16(A0, B, acc[0][cb], 0, 0, 0);
                acc[1][cb] = __builtin_amdgcn_mfma_f32_16x16x32_bf16(A1, B, acc[1][cb], 0, 0, 0);
            }
        }
#pragma unroll
        for (int m = 0; m < 2; ++m) {
#pragma unroll
            for (int i = 0; i < 4; ++i) {
                int gr = row0 + m * 16 + kg * 4 + i;
                if (gr < N) {
#pragma unroll
                    for (int cb = 0; cb < 4; ++cb) {
                        uint32_t p = f2bf_rne(acc[m][cb][i]) |
                                     (f2bf_rne(acc[m][cb + 4][i]) << 16);
                        S[(size_t)gr * 64 + cb * 16 + c16] = p;
                    }
                }
            }
        }
    } else {
        // ---------- build: count -> reserve -> scatter ----------
        const int blk = blockIdx.x - GB;
        const int t = threadIdx.x;
        for (int i = t; i < nbuck; i += 256) h[i] = 0;
        __syncthreads();
        int lo = blk * chunk, hi = min(E, lo + chunk);
        for (int e = lo + t; e < hi; e += 256) atomicAdd(&h[row[e] >> BSHIFT], 1);
        __syncthreads();
        for (int b = t; b < nbuck; b += 256) {
            int c = h[b];
            h[b] = (c > 0) ? atomicAdd(&gcur[b], c) : 0;
        }
        __syncthreads();
        for (int e = lo + t; e < hi; e += 256) {
            int r = row[e], c = col[e];
            int b = r >> BSHIFT;
            int pos = atomicAdd(&h[b], 1);
            if (pos < cap)
                part[(size_t)b * cap + pos] = ((uint32_t)(r & (NPB - 1)) << 17) | (uint32_t)c;
        }
    }
}

// ---------------- P3: per-bucket CSR build (one block per bucket) -----------
__global__ __launch_bounds__(256) void p3_build(const uint32_t* __restrict__ part,
                                                const int* __restrict__ gcur,
                                                int* __restrict__ rowstart,
                                                int* __restrict__ rowend,
                                                float* __restrict__ dis,
                                                int* __restrict__ csr,
                                                int N, int nbuck, int cap) {
    __shared__ int hist[NPB];
    __shared__ int lstart[NPB];
    __shared__ int sbuf[NPB];
    const int b = blockIdx.x, t = threadIdx.x;
    const int base = b * cap;
    int cb = gcur[b];
    if (cb > cap) cb = cap;

    if (t < NPB) hist[t] = 0;
    __syncthreads();
    for (int e = base + t; e < base + cb; e += 256)
        atomicAdd(&hist[part[e] >> 17], 1);
    __syncthreads();

    // exclusive scan of hist[0..127]
    int v = (t < NPB) ? hist[t] : 0;
    if (t < NPB) sbuf[t] = v;
    __syncthreads();
#pragma unroll
    for (int o = 1; o < NPB; o <<= 1) {
        int u = 0;
        if (t < NPB && t >= o) u = sbuf[t - o];
        __syncthreads();
        if (t < NPB && t >= o) sbuf[t] += u;
        __syncthreads();
    }
    if (t < NPB) {
        int ex = sbuf[t] - v;
        lstart[t] = ex;
        int node = (b << BSHIFT) + t;
        if (node < N) {
            rowstart[node] = base + ex;
            rowend[node]   = base + ex + v;
            dis[node]      = rsqrtf((float)v);
        }
        hist[t] = ex;       // reuse as cursor
    }
    __syncthreads();
    for (int e = base + t; e < base + cb; e += 256) {
        uint32_t p = part[e];
        int pos = base + atomicAdd(&hist[p >> 17], 1);
        csr[pos] = (int)(p & 0x1FFFFu);
    }
}

// ---------------- wide gather: 4 edges per VMEM instr (at roofline) ---------
__global__ __launch_bounds__(256) void gather_kernel(const int* __restrict__ csr,
                                                     const int* __restrict__ rowstart,
                                                     const int* __restrict__ rowend,
                                                     const float* __restrict__ dis,
                                                     const uint4* __restrict__ sup,
                                                     const float* __restrict__ bias,
                                                     float* __restrict__ out, int N) {
    int wid  = (blockIdx.x * blockDim.x + threadIdx.x) >> 6;
    int lane = threadIdx.x & 63;
    if (wid >= N) return;
    const int grp = lane >> 4;
    const int li  = lane & 15;
    int begin = rowstart[wid];
    int end   = rowend[wid];
    int endm1 = end - 1;
    float dr  = dis[wid];

    float4 aL = make_float4(0.f, 0.f, 0.f, 0.f);
    float4 aH = make_float4(0.f, 0.f, 0.f, 0.f);

    for (int j = begin; j < end; j += 8) {
        int e0 = j + grp, e1 = j + 4 + grp;
        int c0 = csr[min(e0, endm1)];
        int c1 = csr[min(e1, endm1)];
        float n0 = (e0 < end) ? dr * dis[c0] : 0.f;
        float n1 = (e1 < end) ? dr * dis[c1] : 0.f;
        uint4 u0 = sup[(size_t)c0 * 16 + li];
        uint4 u1 = sup[(size_t)c1 * 16 + li];
        aL.x += n0 * bf_lo(u0.x) + n1 * bf_lo(u1.x);
        aL.y += n0 * bf_lo(u0.y) + n1 * bf_lo(u1.y);
        aL.z += n0 * bf_lo(u0.z) + n1 * bf_lo(u1.z);
        aL.w += n0 * bf_lo(u0.w) + n1 * bf_lo(u1.w);
        aH.x += n0 * bf_hi(u0.x) + n1 * bf_hi(u1.x);
        aH.y += n0 * bf_hi(u0.y) + n1 * bf_hi(u1.y);
        aH.z += n0 * bf_hi(u0.z) + n1 * bf_hi(u1.z);
        aH.w += n0 * bf_hi(u0.w) + n1 * bf_hi(u1.w);
    }

#pragma unroll
    for (int off = 16; off < 64; off <<= 1) {
        aL.x += __shfl_xor(aL.x, off);
        aL.y += __shfl_xor(aL.y, off);
        aL.z += __shfl_xor(aL.z, off);
        aL.w += __shfl_xor(aL.w, off);
        aH.x += __shfl_xor(aH.x, off);
        aH.y += __shfl_xor(aH.y, off);
        aH.z += __shfl_xor(aH.z, off);
        aH.w += __shfl_xor(aH.w, off);
    }

    if (grp == 0) {
        float4 bL = *(const float4*)(bias + li * 4);
        float4 bH = *(const float4*)(bias + 64 + li * 4);
        aL.x += bL.x; aL.y += bL.y; aL.z += bL.z; aL.w += bL.w;
        aH.x += bH.x; aH.y += bH.y; aH.z += bH.z; aH.w += bH.w;
        *(float4*)(out + (size_t)wid * 128 + li * 4)      = aL;
        *(float4*)(out + (size_t)wid * 128 + 64 + li * 4) = aH;
    }
}

// ---------------- fallback path (global-atomic CSR build, fp32 GEMM) --------
#define SCAN_B 256
__global__ void scan_block_kernel(const int* __restrict__ in, int* __restrict__ outp,
                                  int* __restrict__ bsum, int M) {
    __shared__ int s[SCAN_B];
    int t = threadIdx.x;
    int g = blockIdx.x * SCAN_B + t;
    int v = (g < M) ? in[g] : 0;
    s[t] = v;
    __syncthreads();
#pragma unroll
    for (int off = 1; off < SCAN_B; off <<= 1) {
        int u = (t >= off) ? s[t - off] : 0;
        __syncthreads();
        s[t] += u;
        __syncthreads();
    }
    if (g < M) outp[g] = s[t] - v;
    if (t == SCAN_B - 1) bsum[blockIdx.x] = s[t];
}
__global__ void scan_bsum_kernel(int* __restrict__ bsum, int NB) {
    __shared__ int s[1024];
    int t = threadIdx.x;
    int v = (t < NB) ? bsum[t] : 0;
    s[t] = v;
    __syncthreads();
#pragma unroll
    for (int off = 1; off < 1024; off <<= 1) {
        int u = (t >= off) ? s[t - off] : 0;
        __syncthreads();
        s[t] += u;
        __syncthreads();
    }
    if (t < NB) bsum[t] = s[t] - v;
}
__global__ void scan_add_kernel(int* __restrict__ outp, const int* __restrict__ bsum, int M) {
    int g = blockIdx.x * blockDim.x + threadIdx.x;
    if (g < M) outp[g] += bsum[g >> 8];
}
#define GB_M 64
#define GB_KC 32
__global__ __launch_bounds__(256) void gemm_kernel(const float* __restrict__ X,
                                                   const float* __restrict__ W,
                                                   uint32_t* __restrict__ S, int N) {
    __shared__ float sXT[GB_KC][72];
    __shared__ float sW[GB_KC][128];
    const int t  = threadIdx.x;
    const int tx = t & 15;
    const int ty = t >> 4;
    const int bm = blockIdx.x * GB_M;

    float acc[4][8];
#pragma unroll
    for (int i = 0; i < 4; ++i)
#pragma unroll
        for (int j = 0; j < 8; ++j) acc[i][j] = 0.f;

    const int sr = t >> 2;
    const int sc = (t & 3) << 2;

    for (int k0 = 0; k0 < 128; k0 += GB_KC) {
#pragma unroll
        for (int h = 0; h < 2; ++h) {
            int kk = sc + h * 16;
            int gr = bm + sr;
            float4 v = make_float4(0.f, 0.f, 0.f, 0.f);
            if (gr < N) v = *(const float4*)(X + (size_t)gr * 128 + k0 + kk);
            sXT[kk + 0][sr] = v.x;
            sXT[kk + 1][sr] = v.y;
            sXT[kk + 2][sr] = v.z;
            sXT[kk + 3][sr] = v.w;
        }
#pragma unroll
        for (int h = 0; h < 4; ++h) {
            int idx = t + h * 256;
            int wk  = idx >> 5;
            int wo  = (idx & 31) << 2;
            *(float4*)&sW[wk][wo] = *(const float4*)(W + (size_t)(k0 + wk) * 128 + wo);
        }
        __syncthreads();
#pragma unroll
        for (int k = 0; k < GB_KC; ++k) {
            float4 a  = *(const float4*)&sXT[k][ty * 4];
            float4 b0 = *(const float4*)&sW[k][tx * 4];
            float4 b1 = *(const float4*)&sW[k][64 + tx * 4];
            float av[4] = {a.x, a.y, a.z, a.w};
            float bv[8] = {b0.x, b0.y, b0.z, b0.w, b1.x, b1.y, b1.z, b1.w};
#pragma unroll
            for (int i = 0; i < 4; ++i)
#pragma unroll
                for (int j = 0; j < 8; ++j) acc[i][j] += av[i] * bv[j];
        }
        __syncthreads();
    }
#pragma unroll
    for (int i = 0; i < 4; ++i) {
        int gr = bm + ty * 4 + i;
        if (gr < N) {
            uint4 q;
            q.x = f2bf_rne(acc[i][0]) | (f2bf_rne(acc[i][4]) << 16);
            q.y = f2bf_rne(acc[i][1]) | (f2bf_rne(acc[i][5]) << 16);
            q.z = f2bf_rne(acc[i][2]) | (f2bf_rne(acc[i][6]) << 16);
            q.w = f2bf_rne(acc[i][3]) | (f2bf_rne(acc[i][7]) << 16);
            *(uint4*)(S + (size_t)gr * 64 + tx * 4) = q;
        }
    }
}
__global__ void deg_i_kernel(const int* __restrict__ row, int* __restrict__ degi, int E) {
    int g = blockIdx.x * blockDim.x + threadIdx.x;
    if (g < E) atomicAdd(&degi[row[g]], 1);
}
__global__ void rsqrt_i_kernel(const int* __restrict__ degi, float* __restrict__ dis, int N) {
    int g = blockIdx.x * blockDim.x + threadIdx.x;
    if (g < N) dis[g] = rsqrtf((float)degi[g]);
}
__global__ void fill_kernel(const int* __restrict__ row, const int* __restrict__ col,
                            int* __restrict__ start, int* __restrict__ csr, int E) {
    int e = blockIdx.x * blockDim.x + threadIdx.x;
    if (e < E) {
        int pos = atomicAdd(&start[row[e]], 1);
        csr[pos] = col[e];
    }
}
__global__ void rowptr_from_start_kernel(const int* __restrict__ startv,
                                         int* __restrict__ rowptr, int N, int E) {
    int g = blockIdx.x * blockDim.x + threadIdx.x;
    if (g < N) rowptr[g] = startv[g];
    if (g == 0) rowptr[N] = E;
}

extern "C" void kernel_launch(void* const* d_in, const int* in_sizes, int n_in,
                              void* d_out, int out_size, void* d_ws, size_t ws_size,
                              hipStream_t stream) {
    const float* x    = (const float*)d_in[0];
    const int*   ei   = (const int*)d_in[1];
    const float* W    = (const float*)d_in[2];
    const float* bias = (const float*)d_in[3];
    float*       out  = (float*)d_out;

    const int N = in_sizes[0] / 128;
    const int E = in_sizes[1] / 2;
    const int* row = ei;
    const int* col = ei + E;

    const int nbuck = (N + NPB - 1) >> BSHIFT;
    int cap = (E + nbuck - 1) / nbuck;
    cap += cap / 4 + 64;
    cap = (cap + 63) & ~63;
    const int chunkB = (E + NBLK_B - 1) / NBLK_B;
    const int GB = (N + 127) / 128;

    auto al = [](size_t v) { return (v + 511) & ~(size_t)511; };
    size_t o_gcur = 0;
    size_t o_rs   = al(o_gcur + (size_t)nbuck * 4);
    size_t o_re   = al(o_rs + (size_t)N * 4);
    size_t o_dis  = al(o_re + (size_t)N * 4);
    size_t o_csr  = al(o_dis + (size_t)N * 4);
    size_t o_part = al(o_csr + (size_t)nbuck * cap * 4);
    size_t o_wt   = al(o_part + (size_t)nbuck * cap * 4);
    size_t o_sup  = al(o_wt + 128 * 128 * 2);
    size_t need   = o_sup + (size_t)N * 256;   // bf16 support

    char* ws = (char*)d_ws;

    if (ws_size >= need && nbuck <= 1024 && N <= (1 << 17)) {
        int*      gcur = (int*)(ws + o_gcur);
        int*      rs   = (int*)(ws + o_rs);
        int*      re   = (int*)(ws + o_re);
        float*    dis  = (float*)(ws + o_dis);
        int*      csr  = (int*)(ws + o_csr);
        uint32_t* part = (uint32_t*)(ws + o_part);
        ushort*   wt   = (ushort*)(ws + o_wt);
        uint4*    sup  = (uint4*)(ws + o_sup);

        wconv_kernel<<<64, 256, 0, stream>>>(W, wt, gcur, nbuck);
        merged_kernel<<<GB + NBLK_B, 256, 0, stream>>>(
            x, wt, (uint32_t*)sup, N, row, col, part, gcur,
            E, chunkB, nbuck, cap, GB);
        p3_build<<<nbuck, 256, 0, stream>>>(part, gcur, rs, re, dis, csr,
                                            N, nbuck, cap);
        long long gthreads = (long long)N * 64;
        gather_kernel<<<(int)((gthreads + 255) / 256), 256, 0, stream>>>(
            csr, rs, re, dis, sup, bias, out, N);
    } else {
        // fallback: global-atomic CSR build + fp32 LDS GEMM + same gather
        size_t f_degi   = 0;
        size_t f_dis    = al(f_degi + (size_t)N * 4);
        size_t f_start  = al(f_dis + (size_t)N * 4);
        size_t f_rowptr = al(f_start + (size_t)N * 4);
        size_t f_bsum   = al(f_rowptr + ((size_t)N + 1) * 4);
        size_t f_csr    = al(f_bsum + 4096 * 4);
        size_t f_sup    = al(f_csr + (size_t)E * 4);

        int*      degi   = (int*)(ws + f_degi);
        float*    dis    = (float*)(ws + f_dis);
        int*      startv = (int*)(ws + f_start);
        int*      rowptr = (int*)(ws + f_rowptr);
        int*      bsum   = (int*)(ws + f_bsum);
        int*      csr    = (int*)(ws + f_csr);
        uint4*    sup    = (uint4*)(ws + f_sup);
        const int NBn = (N + SCAN_B - 1) / SCAN_B;

        hipMemsetAsync(degi, 0, (size_t)N * 4, stream);
        gemm_kernel<<<(N + GB_M - 1) / GB_M, 256, 0, stream>>>(x, W, (uint32_t*)sup, N);
        deg_i_kernel<<<(E + 255) / 256, 256, 0, stream>>>(row, degi, E);
        scan_block_kernel<<<NBn, SCAN_B, 0, stream>>>(degi, startv, bsum, N);
        scan_bsum_kernel<<<1, 1024, 0, stream>>>(bsum, NBn);
        scan_add_kernel<<<NBn, SCAN_B, 0, stream>>>(startv, bsum, N);
        rowptr_from_start_kernel<<<NBn, SCAN_B, 0, stream>>>(startv, rowptr, N, E);
        rsqrt_i_kernel<<<NBn, SCAN_B, 0, stream>>>(degi, dis, N);
        fill_kernel<<<(E + 255) / 256, 256, 0, stream>>>(row, col, startv, csr, E);
        long long gthreads = (long long)N * 64;
        gather_kernel<<<(int)((gthreads + 255) / 256), 256, 0, stream>>>(
            csr, rowptr, rowptr + 1, dis, sup, bias, out, N);
    }
}

// Round 9
// 133.779 us; speedup vs baseline: 11.4309x; 1.0933x over previous
//
#include <hip/hip_runtime.h>
#include <hip/hip_bf16.h>

// GCNConv: out = scatter_add_row( norm[e] * (x@W)[col[e]] ) + bias
// Round 9: kill scattered-4B-store transactions. Merged build counting-sorts
// its chunk in LDS and writes part as coalesced bucket runs; p3 builds the
// csr image in LDS and streams it out sequentially. Gather (roofline) untouched.

#define NBLK_B  512     // build blocks in merged kernel
#define BSHIFT  8       // 256 nodes per bucket
#define NPB     256
#define REC_CAP 3456    // max edges per build block chunk
#define CAPMAX  5632    // max records per bucket

typedef __attribute__((ext_vector_type(8))) short bf16x8;
typedef __attribute__((ext_vector_type(4))) float f32x4;

__device__ __forceinline__ uint32_t f2bf_rne(float f) {
    uint32_t u = __float_as_uint(f);
    return (u + 0x7fffu + ((u >> 16) & 1u)) >> 16;
}
__device__ __forceinline__ float bf_lo(uint32_t u) { return __uint_as_float(u << 16); }
__device__ __forceinline__ float bf_hi(uint32_t u) { return __uint_as_float(u & 0xffff0000u); }

__device__ __forceinline__ bf16x8 pack8(float4 lo, float4 hi) {
    union { bf16x8 v; ushort u[8]; } r;
    r.u[0] = (ushort)f2bf_rne(lo.x);
    r.u[1] = (ushort)f2bf_rne(lo.y);
    r.u[2] = (ushort)f2bf_rne(lo.z);
    r.u[3] = (ushort)f2bf_rne(lo.w);
    r.u[4] = (ushort)f2bf_rne(hi.x);
    r.u[5] = (ushort)f2bf_rne(hi.y);
    r.u[6] = (ushort)f2bf_rne(hi.z);
    r.u[7] = (ushort)f2bf_rne(hi.w);
    return r.v;
}

// ---------------- W -> Wt bf16 transposed; also zero bucket cursors ---------
__global__ void wconv_kernel(const float* __restrict__ W, ushort* __restrict__ Wt,
                             int* __restrict__ gcur, int nbuck) {
    int t = blockIdx.x * blockDim.x + threadIdx.x;   // 0..16383
    int n = t >> 7, k = t & 127;
    Wt[n * 128 + k] = (ushort)f2bf_rne(W[k * 128 + n]);
    if (t < nbuck) gcur[t] = 0;
}

// ---------------- merged: MFMA GEMM blocks + LDS-sorted partition blocks ----
__global__ __launch_bounds__(256) void merged_kernel(
        const float* __restrict__ X, const ushort* __restrict__ Wt,
        uint32_t* __restrict__ S, int N,
        const int* __restrict__ row, const int* __restrict__ col,
        uint32_t* __restrict__ part, int* __restrict__ gcur,
        int E, int chunk, int nbuck, int cap, int GB) {
    __shared__ __align__(16) char smem[26880];
    if ((int)blockIdx.x < GB) {
        // ---------- GEMM: S[N,128](bf16 pairs ch,ch+64) = X @ W ----------
        const int wave = threadIdx.x >> 6;
        const int lane = threadIdx.x & 63;
        const int c16  = lane & 15;
        const int kg   = lane >> 4;
        const int row0 = blockIdx.x * 128 + wave * 32;

        int rA0 = row0 + c16;
        int rA1 = row0 + 16 + c16;
        if (rA0 >= N) rA0 = N - 1;
        if (rA1 >= N) rA1 = N - 1;

        f32x4 acc[2][8];
#pragma unroll
        for (int m = 0; m < 2; ++m)
#pragma unroll
            for (int cb = 0; cb < 8; ++cb) acc[m][cb] = (f32x4){0.f, 0.f, 0.f, 0.f};

        const float*  xa0 = X + (size_t)rA0 * 128 + kg * 8;
        const float*  xa1 = X + (size_t)rA1 * 128 + kg * 8;
        const ushort* wb  = Wt + kg * 8 + c16 * 128;

#pragma unroll
        for (int kk = 0; kk < 4; ++kk) {
            float4 a0lo = *(const float4*)(xa0 + kk * 32);
            float4 a0hi = *(const float4*)(xa0 + kk * 32 + 4);
            float4 a1lo = *(const float4*)(xa1 + kk * 32);
            float4 a1hi = *(const float4*)(xa1 + kk * 32 + 4);
            bf16x8 A0 = pack8(a0lo, a0hi);
            bf16x8 A1 = pack8(a1lo, a1hi);
#pragma unroll
            for (int cb = 0; cb < 8; ++cb) {
                bf16x8 B = *(const bf16x8*)(wb + (size_t)cb * 16 * 128 + kk * 32);
                acc[0][cb] = __builtin_amdgcn_mfma_f32_16x16x32_bf16(A0, B, acc[0][cb], 0, 0, 0);
                acc[1][cb] = __builtin_amdgcn_mfma_f32_16x16x32_bf16(A1, B, acc[1][cb], 0, 0, 0);
            }
        }
#pragma unroll
        for (int m = 0; m < 2; ++m) {
#pragma unroll
            for (int i = 0; i < 4; ++i) {
                int gr = row0 + m * 16 + kg * 4 + i;
                if (gr < N) {
#pragma unroll
                    for (int cb = 0; cb < 4; ++cb) {
                        uint32_t p = f2bf_rne(acc[m][cb][i]) |
                                     (f2bf_rne(acc[m][cb + 4][i]) << 16);
                        S[(size_t)gr * 64 + cb * 16 + c16] = p;
                    }
                }
            }
        }
    } else {
        // ---------- build: LDS counting-sort, coalesced part write ----------
        uint32_t* rec  = (uint32_t*)smem;                 // [REC_CAP]
        ushort*   rbk  = (ushort*)(smem + 13824);         // [REC_CAP]
        int*      hist = (int*)(smem + 20736);            // [512]
        int*      lst  = (int*)(smem + 22784);            // [512]
        int*      resv = (int*)(smem + 24832);            // [512]
        const int blk = blockIdx.x - GB;
        const int t = threadIdx.x;
        int lo = blk * chunk, hi = min(E, lo + chunk);
        int cnt = hi - lo;

        for (int i = t; i < 512; i += 256) hist[i] = 0;
        __syncthreads();
        // pass 1: histogram by bucket
        for (int i = t; i < cnt; i += 256)
            atomicAdd(&hist[row[lo + i] >> BSHIFT], 1);
        __syncthreads();
        // exclusive scan of hist[0..511] (2 per thread; resv as scratch)
        int a0 = hist[2 * t], a1 = hist[2 * t + 1];
        int v2 = a0 + a1;
        resv[t] = v2;
        __syncthreads();
#pragma unroll
        for (int o = 1; o < 256; o <<= 1) {
            int u = (t >= o) ? resv[t - o] : 0;
            __syncthreads();
            resv[t] += u;
            __syncthreads();
        }
        int ex = resv[t] - v2;
        lst[2 * t]     = ex;
        lst[2 * t + 1] = ex + a0;
        __syncthreads();
        // reserve global ranges per bucket
        for (int b = t; b < nbuck; b += 256) {
            int c = hist[b];
            resv[b] = (c > 0) ? atomicAdd(&gcur[b], c) : 0;
        }
        __syncthreads();
        // cursors = local starts
        for (int i = t; i < 512; i += 256) hist[i] = lst[i];
        __syncthreads();
        // pass 2: re-read edges, scatter into LDS sorted order
        for (int i = t; i < cnt; i += 256) {
            int r = row[lo + i], c = col[lo + i];
            int b = r >> BSHIFT;
            int p = atomicAdd(&hist[b], 1);
            rec[p] = ((uint32_t)(r & (NPB - 1)) << 17) | (uint32_t)c;
            rbk[p] = (ushort)b;
        }
        __syncthreads();
        // coalesced write-out: per-bucket contiguous runs
        for (int i = t; i < cnt; i += 256) {
            int b = rbk[i];
            int off = resv[b] + (i - lst[b]);
            if (off < cap)
                part[(size_t)b * cap + off] = rec[i];
        }
    }
}

// ---------------- P3: per-bucket CSR via LDS image, coalesced out -----------
__global__ __launch_bounds__(512) void p3_build(const uint32_t* __restrict__ part,
                                                const int* __restrict__ gcur,
                                                int* __restrict__ rowstart,
                                                int* __restrict__ rowend,
                                                float* __restrict__ dis,
                                                int* __restrict__ csr,
                                                int N, int nbuck, int cap) {
    __shared__ uint32_t recl[CAPMAX];
    __shared__ int csrl[CAPMAX];
    __shared__ int hist[NPB];
    __shared__ int lst[NPB];
    __shared__ int s[NPB];
    const int b = blockIdx.x, t = threadIdx.x;
    const int base = b * cap;
    int cb = gcur[b];
    if (cb > cap) cb = cap;

    if (t < NPB) hist[t] = 0;
    __syncthreads();
    for (int i = t; i < cb; i += 512) {
        uint32_t p = part[base + i];
        recl[i] = p;
        atomicAdd(&hist[p >> 17], 1);
    }
    __syncthreads();

    int v = 0;
    if (t < NPB) { v = hist[t]; s[t] = v; }
    __syncthreads();
#pragma unroll
    for (int o = 1; o < NPB; o <<= 1) {
        int u = 0;
        if (t < NPB && t >= o) u = s[t - o];
        __syncthreads();
        if (t < NPB && t >= o) s[t] += u;
        __syncthreads();
    }
    if (t < NPB) {
        int ex = s[t] - v;
        lst[t] = ex;
        int node = (b << BSHIFT) + t;
        if (node < N) {
            rowstart[node] = base + ex;
            rowend[node]   = base + ex + v;
            dis[node]      = rsqrtf((float)v);
        }
        hist[t] = ex;    // cursor
    }
    __syncthreads();
    for (int i = t; i < cb; i += 512) {
        uint32_t p = recl[i];
        int q = atomicAdd(&hist[p >> 17], 1);
        csrl[q] = (int)(p & 0x1FFFFu);
    }
    __syncthreads();
    for (int i = t; i < cb; i += 512)
        csr[base + i] = csrl[i];
}

// ---------------- wide gather: 4 edges per VMEM instr (at roofline) ---------
__global__ __launch_bounds__(256) void gather_kernel(const int* __restrict__ csr,
                                                     const int* __restrict__ rowstart,
                                                     const int* __restrict__ rowend,
                                                     const float* __restrict__ dis,
                                                     const uint4* __restrict__ sup,
                                                     const float* __restrict__ bias,
                                                     float* __restrict__ out, int N) {
    int wid  = (blockIdx.x * blockDim.x + threadIdx.x) >> 6;
    int lane = threadIdx.x & 63;
    if (wid >= N) return;
    const int grp = lane >> 4;
    const int li  = lane & 15;
    int begin = rowstart[wid];
    int end   = rowend[wid];
    int endm1 = end - 1;
    float dr  = dis[wid];

    float4 aL = make_float4(0.f, 0.f, 0.f, 0.f);
    float4 aH = make_float4(0.f, 0.f, 0.f, 0.f);

    for (int j = begin; j < end; j += 8) {
        int e0 = j + grp, e1 = j + 4 + grp;
        int c0 = csr[min(e0, endm1)];
        int c1 = csr[min(e1, endm1)];
        float n0 = (e0 < end) ? dr * dis[c0] : 0.f;
        float n1 = (e1 < end) ? dr * dis[c1] : 0.f;
        uint4 u0 = sup[(size_t)c0 * 16 + li];
        uint4 u1 = sup[(size_t)c1 * 16 + li];
        aL.x += n0 * bf_lo(u0.x) + n1 * bf_lo(u1.x);
        aL.y += n0 * bf_lo(u0.y) + n1 * bf_lo(u1.y);
        aL.z += n0 * bf_lo(u0.z) + n1 * bf_lo(u1.z);
        aL.w += n0 * bf_lo(u0.w) + n1 * bf_lo(u1.w);
        aH.x += n0 * bf_hi(u0.x) + n1 * bf_hi(u1.x);
        aH.y += n0 * bf_hi(u0.y) + n1 * bf_hi(u1.y);
        aH.z += n0 * bf_hi(u0.z) + n1 * bf_hi(u1.z);
        aH.w += n0 * bf_hi(u0.w) + n1 * bf_hi(u1.w);
    }

#pragma unroll
    for (int off = 16; off < 64; off <<= 1) {
        aL.x += __shfl_xor(aL.x, off);
        aL.y += __shfl_xor(aL.y, off);
        aL.z += __shfl_xor(aL.z, off);
        aL.w += __shfl_xor(aL.w, off);
        aH.x += __shfl_xor(aH.x, off);
        aH.y += __shfl_xor(aH.y, off);
        aH.z += __shfl_xor(aH.z, off);
        aH.w += __shfl_xor(aH.w, off);
    }

    if (grp == 0) {
        float4 bL = *(const float4*)(bias + li * 4);
        float4 bH = *(const float4*)(bias + 64 + li * 4);
        aL.x += bL.x; aL.y += bL.y; aL.z += bL.z; aL.w += bL.w;
        aH.x += bH.x; aH.y += bH.y; aH.z += bH.z; aH.w += bH.w;
        *(float4*)(out + (size_t)wid * 128 + li * 4)      = aL;
        *(float4*)(out + (size_t)wid * 128 + 64 + li * 4) = aH;
    }
}

// ---------------- fallback path (global-atomic CSR build, fp32 GEMM) --------
#define SCAN_B 256
__global__ void scan_block_kernel(const int* __restrict__ in, int* __restrict__ outp,
                                  int* __restrict__ bsum, int M) {
    __shared__ int s[SCAN_B];
    int t = threadIdx.x;
    int g = blockIdx.x * SCAN_B + t;
    int v = (g < M) ? in[g] : 0;
    s[t] = v;
    __syncthreads();
#pragma unroll
    for (int off = 1; off < SCAN_B; off <<= 1) {
        int u = (t >= off) ? s[t - off] : 0;
        __syncthreads();
        s[t] += u;
        __syncthreads();
    }
    if (g < M) outp[g] = s[t] - v;
    if (t == SCAN_B - 1) bsum[blockIdx.x] = s[t];
}
__global__ void scan_bsum_kernel(int* __restrict__ bsum, int NB) {
    __shared__ int s[1024];
    int t = threadIdx.x;
    int v = (t < NB) ? bsum[t] : 0;
    s[t] = v;
    __syncthreads();
#pragma unroll
    for (int off = 1; off < 1024; off <<= 1) {
        int u = (t >= off) ? s[t - off] : 0;
        __syncthreads();
        s[t] += u;
        __syncthreads();
    }
    if (t < NB) bsum[t] = s[t] - v;
}
__global__ void scan_add_kernel(int* __restrict__ outp, const int* __restrict__ bsum, int M) {
    int g = blockIdx.x * blockDim.x + threadIdx.x;
    if (g < M) outp[g] += bsum[g >> 8];
}
#define GB_M 64
#define GB_KC 32
__global__ __launch_bounds__(256) void gemm_kernel(const float* __restrict__ X,
                                                   const float* __restrict__ W,
                                                   uint32_t* __restrict__ S, int N) {
    __shared__ float sXT[GB_KC][72];
    __shared__ float sW[GB_KC][128];
    const int t  = threadIdx.x;
    const int tx = t & 15;
    const int ty = t >> 4;
    const int bm = blockIdx.x * GB_M;

    float acc[4][8];
#pragma unroll
    for (int i = 0; i < 4; ++i)
#pragma unroll
        for (int j = 0; j < 8; ++j) acc[i][j] = 0.f;

    const int sr = t >> 2;
    const int sc = (t & 3) << 2;

    for (int k0 = 0; k0 < 128; k0 += GB_KC) {
#pragma unroll
        for (int h = 0; h < 2; ++h) {
            int kk = sc + h * 16;
            int gr = bm + sr;
            float4 v = make_float4(0.f, 0.f, 0.f, 0.f);
            if (gr < N) v = *(const float4*)(X + (size_t)gr * 128 + k0 + kk);
            sXT[kk + 0][sr] = v.x;
            sXT[kk + 1][sr] = v.y;
            sXT[kk + 2][sr] = v.z;
            sXT[kk + 3][sr] = v.w;
        }
#pragma unroll
        for (int h = 0; h < 4; ++h) {
            int idx = t + h * 256;
            int wk  = idx >> 5;
            int wo  = (idx & 31) << 2;
            *(float4*)&sW[wk][wo] = *(const float4*)(W + (size_t)(k0 + wk) * 128 + wo);
        }
        __syncthreads();
#pragma unroll
        for (int k = 0; k < GB_KC; ++k) {
            float4 a  = *(const float4*)&sXT[k][ty * 4];
            float4 b0 = *(const float4*)&sW[k][tx * 4];
            float4 b1 = *(const float4*)&sW[k][64 + tx * 4];
            float av[4] = {a.x, a.y, a.z, a.w};
            float bv[8] = {b0.x, b0.y, b0.z, b0.w, b1.x, b1.y, b1.z, b1.w};
#pragma unroll
            for (int i = 0; i < 4; ++i)
#pragma unroll
                for (int j = 0; j < 8; ++j) acc[i][j] += av[i] * bv[j];
        }
        __syncthreads();
    }
#pragma unroll
    for (int i = 0; i < 4; ++i) {
        int gr = bm + ty * 4 + i;
        if (gr < N) {
            uint4 q;
            q.x = f2bf_rne(acc[i][0]) | (f2bf_rne(acc[i][4]) << 16);
            q.y = f2bf_rne(acc[i][1]) | (f2bf_rne(acc[i][5]) << 16);
            q.z = f2bf_rne(acc[i][2]) | (f2bf_rne(acc[i][6]) << 16);
            q.w = f2bf_rne(acc[i][3]) | (f2bf_rne(acc[i][7]) << 16);
            *(uint4*)(S + (size_t)gr * 64 + tx * 4) = q;
        }
    }
}
__global__ void deg_i_kernel(const int* __restrict__ row, int* __restrict__ degi, int E) {
    int g = blockIdx.x * blockDim.x + threadIdx.x;
    if (g < E) atomicAdd(&degi[row[g]], 1);
}
__global__ void rsqrt_i_kernel(const int* __restrict__ degi, float* __restrict__ dis, int N) {
    int g = blockIdx.x * blockDim.x + threadIdx.x;
    if (g < N) dis[g] = rsqrtf((float)degi[g]);
}
__global__ void fill_kernel(const int* __restrict__ row, const int* __restrict__ col,
                            int* __restrict__ start, int* __restrict__ csr, int E) {
    int e = blockIdx.x * blockDim.x + threadIdx.x;
    if (e < E) {
        int pos = atomicAdd(&start[row[e]], 1);
        csr[pos] = col[e];
    }
}
__global__ void rowptr_from_start_kernel(const int* __restrict__ startv,
                                         int* __restrict__ rowptr, int N, int E) {
    int g = blockIdx.x * blockDim.x + threadIdx.x;
    if (g < N) rowptr[g] = startv[g];
    if (g == 0) rowptr[N] = E;
}

extern "C" void kernel_launch(void* const* d_in, const int* in_sizes, int n_in,
                              void* d_out, int out_size, void* d_ws, size_t ws_size,
                              hipStream_t stream) {
    const float* x    = (const float*)d_in[0];
    const int*   ei   = (const int*)d_in[1];
    const float* W    = (const float*)d_in[2];
    const float* bias = (const float*)d_in[3];
    float*       out  = (float*)d_out;

    const int N = in_sizes[0] / 128;
    const int E = in_sizes[1] / 2;
    const int* row = ei;
    const int* col = ei + E;

    const int nbuck = (N + NPB - 1) >> BSHIFT;
    int cap = (E + nbuck - 1) / nbuck;
    cap += cap / 4 + 128;
    cap = (cap + 63) & ~63;
    const int chunkB = (E + NBLK_B - 1) / NBLK_B;
    const int GB = (N + 127) / 128;

    auto al = [](size_t v) { return (v + 511) & ~(size_t)511; };
    size_t o_gcur = 0;
    size_t o_rs   = al(o_gcur + (size_t)nbuck * 4);
    size_t o_re   = al(o_rs + (size_t)N * 4);
    size_t o_dis  = al(o_re + (size_t)N * 4);
    size_t o_csr  = al(o_dis + (size_t)N * 4);
    size_t o_part = al(o_csr + (size_t)nbuck * cap * 4);
    size_t o_wt   = al(o_part + (size_t)nbuck * cap * 4);
    size_t o_sup  = al(o_wt + 128 * 128 * 2);
    size_t need   = o_sup + (size_t)N * 256;   // bf16 support

    char* ws = (char*)d_ws;

    if (ws_size >= need && nbuck <= 512 && N <= (1 << 17) &&
        cap <= CAPMAX && chunkB <= REC_CAP) {
        int*      gcur = (int*)(ws + o_gcur);
        int*      rs   = (int*)(ws + o_rs);
        int*      re   = (int*)(ws + o_re);
        float*    dis  = (float*)(ws + o_dis);
        int*      csr  = (int*)(ws + o_csr);
        uint32_t* part = (uint32_t*)(ws + o_part);
        ushort*   wt   = (ushort*)(ws + o_wt);
        uint4*    sup  = (uint4*)(ws + o_sup);

        wconv_kernel<<<64, 256, 0, stream>>>(W, wt, gcur, nbuck);
        merged_kernel<<<GB + NBLK_B, 256, 0, stream>>>(
            x, wt, (uint32_t*)sup, N, row, col, part, gcur,
            E, chunkB, nbuck, cap, GB);
        p3_build<<<nbuck, 512, 0, stream>>>(part, gcur, rs, re, dis, csr,
                                            N, nbuck, cap);
        long long gthreads = (long long)N * 64;
        gather_kernel<<<(int)((gthreads + 255) / 256), 256, 0, stream>>>(
            csr, rs, re, dis, sup, bias, out, N);
    } else {
        // fallback: global-atomic CSR build + fp32 LDS GEMM + same gather
        size_t f_degi   = 0;
        size_t f_dis    = al(f_degi + (size_t)N * 4);
        size_t f_start  = al(f_dis + (size_t)N * 4);
        size_t f_rowptr = al(f_start + (size_t)N * 4);
        size_t f_bsum   = al(f_rowptr + ((size_t)N + 1) * 4);
        size_t f_csr    = al(f_bsum + 4096 * 4);
        size_t f_sup    = al(f_csr + (size_t)E * 4);

        int*      degi   = (int*)(ws + f_degi);
        float*    dis    = (float*)(ws + f_dis);
        int*      startv = (int*)(ws + f_start);
        int*      rowptr = (int*)(ws + f_rowptr);
        int*      bsum   = (int*)(ws + f_bsum);
        int*      csr    = (int*)(ws + f_csr);
        uint4*    sup    = (uint4*)(ws + f_sup);
        const int NBn = (N + SCAN_B - 1) / SCAN_B;

        hipMemsetAsync(degi, 0, (size_t)N * 4, stream);
        gemm_kernel<<<(N + GB_M - 1) / GB_M, 256, 0, stream>>>(x, W, (uint32_t*)sup, N);
        deg_i_kernel<<<(E + 255) / 256, 256, 0, stream>>>(row, degi, E);
        scan_block_kernel<<<NBn, SCAN_B, 0, stream>>>(degi, startv, bsum, N);
        scan_bsum_kernel<<<1, 1024, 0, stream>>>(bsum, NBn);
        scan_add_kernel<<<NBn, SCAN_B, 0, stream>>>(startv, bsum, N);
        rowptr_from_start_kernel<<<NBn, SCAN_B, 0, stream>>>(startv, rowptr, N, E);
        rsqrt_i_kernel<<<NBn, SCAN_B, 0, stream>>>(degi, dis, N);
        fill_kernel<<<(E + 255) / 256, 256, 0, stream>>>(row, col, startv, csr, E);
        long long gthreads = (long long)N * 64;
        gather_kernel<<<(int)((gthreads + 255) / 256), 256, 0, stream>>>(
            csr, rowptr, rowptr + 1, dis, sup, bias, out, N);
    }
}